// Round 21
// baseline (349.610 us; speedup 1.0000x reference)
//
#include <hip/hip_runtime.h>
#include <math.h>

#define B_    2
#define C_    128
#define N_    2048
#define HID_  512
#define HEADS_ 8
#define EPS_  1e-6f
#define NS_   0.2f
#define KSPLIT 4

typedef __attribute__((ext_vector_type(8))) short short8v;  // 8 bf16
typedef __attribute__((ext_vector_type(4))) float f32x4;
typedef unsigned short ush;
typedef unsigned int u32;

__device__ inline ush f2bf(float f) {
    unsigned u = __float_as_uint(f);
    u += 0x7FFF + ((u >> 16) & 1);          // round-to-nearest-even
    return (ush)(u >> 16);
}
__device__ inline float bf2f(ush u) { return __uint_as_float((u32)u << 16); }

// pack float -> (hi bf16 << 16) | lo bf16
__device__ inline u32 splitpack(float x) {
    ush hi = f2bf(x);
    float hf = __uint_as_float((u32)hi << 16);
    ush lo = f2bf(x - hf);
    return ((u32)hi << 16) | (u32)lo;
}

__device__ inline void unpack_hi(const u32* buf, short8v& h0, short8v& h1) {
    ush h[16];
    #pragma unroll
    for (int j = 0; j < 16; ++j) h[j] = (ush)(buf[j] >> 16);
    h0 = *(short8v*)&h[0]; h1 = *(short8v*)&h[8];
}

// ---------------------------------------------------------------------------
// vec_layernorm, z-indexed multi-input, single global read pass (registers)
// ---------------------------------------------------------------------------
struct LNArgs {
    const float* x[2]; const float* g[2]; const float* bt[2]; ush* ysp[2];
};
__global__ __launch_bounds__(256) void ln_kernel(LNArgs a)
{
    __shared__ float red1[8][32];
    __shared__ float red2[8][32];
    const int s = blockIdx.z;
    const float* x = a.x[s];
    const float* gma = a.g[s];
    const float* bta = a.bt[s];
    ush* ysp = a.ysp[s];

    const int b  = blockIdx.y;
    const int n0 = blockIdx.x * 32;
    const int nn = threadIdx.x & 31;
    const int cg = threadIdx.x >> 5;

    float xr0[16], xr1[16], xr2[16], nrr[16];
    float s1 = 0.f, s2 = 0.f;
    #pragma unroll
    for (int it = 0; it < 16; ++it) {
        int c = it * 8 + cg;
        size_t base = ((size_t)(b * C_ + c) * 3) * N_ + n0 + nn;
        float x0 = x[base], x1 = x[base + N_], x2 = x[base + 2 * N_];
        float nr = sqrtf(x0 * x0 + x1 * x1 + x2 * x2 + EPS_);
        xr0[it] = x0; xr1[it] = x1; xr2[it] = x2; nrr[it] = nr;
        s1 += nr; s2 += nr * nr;
    }
    red1[cg][nn] = s1; red2[cg][nn] = s2;
    __syncthreads();
    float S1 = 0.f, S2 = 0.f;
    #pragma unroll
    for (int g = 0; g < 8; ++g) { S1 += red1[g][nn]; S2 += red2[g][nn]; }
    float mu   = S1 * (1.f / 128.f);
    float var  = S2 * (1.f / 128.f) - mu * mu;
    float rstd = rsqrtf(var + EPS_);

    #pragma unroll
    for (int it = 0; it < 16; ++it) {
        int c = it * 8 + cg;
        float nr = nrr[it];
        float ln = (nr - mu) * rstd * gma[c] + bta[c];
        float sc = ln / (nr + EPS_);
        size_t base = ((size_t)(b * C_ + c) * 3) * N_ + n0 + nn;
        ysp[base]          = f2bf(xr0[it] * sc);
        ysp[base + N_]     = f2bf(xr1[it] * sc);
        ysp[base + 2 * N_] = f2bf(xr2[it] * sc);
    }
}

// ---------------------------------------------------------------------------
// fused setup (NO LDS -> full occupancy for the memory-bound blocks):
//   blocks [0, 8192):    8 weight split-conversions (w = bx>>10)
//   blocks [8192, 8576): output-mix weight products Wfa/Wfb
//   blocks [8576, 9600): qktb zeroing
// ---------------------------------------------------------------------------
struct SetupArgs {
    const float* src[8]; u32* dst[8]; int n[8]; float scale[8];
    const float* Wm[2]; const float* Wo[2]; const float* We[2];
    u32* Wfa[2]; u32* Wfb[2];
    uint4* qkz;
};
__global__ __launch_bounds__(256) void setup_kernel(SetupArgs a)
{
    const int bx = blockIdx.x;
    if (bx < 8192) {
        const int w = bx >> 10;
        const int i = (bx & 1023) * 256 + threadIdx.x;
        if (i < a.n[w]) a.dst[w][i] = splitpack(a.src[w][i] * a.scale[w]);
    } else if (bx < 8576) {
        const int tg = (bx - 8192) * 256 + threadIdx.x;   // 0..98303
        const int p = tg / 49152;
        const int rem = tg % 49152;
        if (rem < 16384) {
            const int o = rem >> 7, k = rem & 127;
            const float* Wm = a.Wm[p];
            const float* Wo = a.Wo[p];
            float acc = 0.f;
            #pragma unroll 4
            for (int c = 0; c < 128; ++c)
                acc += Wm[o * 256 + c] * Wo[c * 128 + k];
            a.Wfa[p][o * 128 + k] = splitpack(acc);
        } else {
            const int r2 = rem - 16384;
            const int o = r2 >> 8, k = r2 & 255;
            const float* Wm = a.Wm[p];
            const float* We = a.We[p];
            float acc = 0.f;
            #pragma unroll 4
            for (int c = 0; c < 128; ++c)
                acc += Wm[o * 256 + 128 + c] * We[c * 256 + k];
            a.Wfb[p][o * 256 + k] = splitpack(acc);
        }
    } else {
        // zero qktb (524288 uint4 = 8.4MB); 1024 blocks x 512 uint4
        const size_t i0 = ((size_t)(bx - 8576) * 256 + threadIdx.x) * 2;
        uint4 z = {0, 0, 0, 0};
        a.qkz[i0]     = z;
        a.qkz[i0 + 1] = z;
    }
}

// ---------------------------------------------------------------------------
// Dfused = Dact*W1 (512x128), LDS-tiled 64x64 GEMM. OWN kernel so its 33KB
// LDS footprint does not throttle the big setup grid. 16 blocks only.
// Accumulation order identical to the scalar reference (kk asc, c asc).
// ---------------------------------------------------------------------------
__global__ __launch_bounds__(256) void dfuse_kernel(
    const float* __restrict__ DactF, const float* __restrict__ W1F,
    u32* __restrict__ Dfused)
{
    __shared__ float As[64][65];
    __shared__ float Bs[64][65];
    const int tb = blockIdx.x;                // 0..15
    const int o0 = (tb >> 1) * 64, k0 = (tb & 1) * 64;
    const int o = threadIdx.x & 63, kq = threadIdx.x >> 6;   // kq 0..3
    float accd[16];
    #pragma unroll
    for (int j = 0; j < 16; ++j) accd[j] = 0.f;
    for (int kk = 0; kk < 512; kk += 64) {
        #pragma unroll
        for (int p = 0; p < 16; ++p) {
            int idx = threadIdx.x + p * 256;
            int r = idx >> 6, cc = idx & 63;
            As[r][cc] = DactF[(size_t)(o0 + r) * 512 + kk + cc];
            Bs[r][cc] = W1F[(size_t)(kk + r) * 128 + k0 + cc];
        }
        __syncthreads();
        #pragma unroll 8
        for (int c = 0; c < 64; ++c) {
            float av = As[o][c];
            #pragma unroll
            for (int j = 0; j < 16; ++j)
                accd[j] += av * Bs[c][kq * 16 + j];
        }
        __syncthreads();
    }
    #pragma unroll
    for (int j = 0; j < 16; ++j)
        Dfused[(size_t)(o0 + o) * 128 + k0 + kq * 16 + j] = splitpack(accd[j]);
}

// ---------------------------------------------------------------------------
// bf16 MFMA GEMM core (hi-only). XBF: X input is bf16 ush (else split u32).
// XMODE 0: X[(b*K + c)*M + m]   XMODE 1: X[((b*N+n)*3+t)*K + c], m = t*N+n
// OMODE 0: fp32(+Z)  3: bf16 Ybf  4: qkv fragment-major
// ---------------------------------------------------------------------------
template <int XMODE, int OMODE, bool XBF>
__device__ __forceinline__ void gemm_tile(
    const u32* __restrict__ Wsp, int wstride,
    const void* __restrict__ Xv, int K,
    const float* __restrict__ Z, float* __restrict__ Y,
    ush* __restrict__ Ybf, ush* __restrict__ Ytr,
    int b, int m0, int o0loc, int oglob, int Ostr,
    ush (*Wh)[64], ush (*Xh)[64])
{
    const int M = 3 * N_;
    const int tid = threadIdx.x;
    const int lane = tid & 63, wv = tid >> 6;
    const int col = lane & 15, grp = lane >> 4;
    const int wo = wv >> 1, wm = wv & 1;

    f32x4 acc[2][2];
    #pragma unroll
    for (int i = 0; i < 2; ++i)
        #pragma unroll
        for (int j = 0; j < 2; ++j) { f32x4 z = {0.f,0.f,0.f,0.f}; acc[i][j] = z; }

    for (int kk = 0; kk < K; kk += 64) {
        {
            const int o = tid >> 2, kg = tid & 3;
            const u32* src = Wsp + (size_t)(o0loc + o) * wstride + kk + kg * 16;
            u32 buf[16];
            #pragma unroll
            for (int j = 0; j < 4; ++j) *(uint4*)&buf[j * 4] = *(const uint4*)(src + j * 4);
            const int s0 = ((kg * 2)     ^ (o & 7)) << 3;
            const int s1 = ((kg * 2 + 1) ^ (o & 7)) << 3;
            short8v h0, h1; unpack_hi(buf, h0, h1);
            *(short8v*)&Wh[o][s0] = h0; *(short8v*)&Wh[o][s1] = h1;
        }
        if (XMODE == 0) {
            const int m = lane, kq = wv;
            const int s0 = ((kq * 2)     ^ (m & 7)) << 3;
            const int s1 = ((kq * 2 + 1) ^ (m & 7)) << 3;
            if (XBF) {
                const ush* src = (const ush*)Xv + ((size_t)b * K + kk + kq * 16) * M + m0 + m;
                ush h[16];
                #pragma unroll
                for (int j = 0; j < 16; ++j) h[j] = src[(size_t)j * M];
                *(short8v*)&Xh[m][s0] = *(short8v*)&h[0];
                *(short8v*)&Xh[m][s1] = *(short8v*)&h[8];
            } else {
                const u32* src = (const u32*)Xv + ((size_t)b * K + kk + kq * 16) * M + m0 + m;
                u32 buf[16];
                #pragma unroll
                for (int j = 0; j < 16; ++j) buf[j] = src[(size_t)j * M];
                short8v h0, h1; unpack_hi(buf, h0, h1);
                *(short8v*)&Xh[m][s0] = h0; *(short8v*)&Xh[m][s1] = h1;
            }
        } else {
            const int m = tid >> 2, kg = tid & 3;
            const int mg = m0 + m;
            const int n = mg & (N_ - 1), t = mg >> 11;
            const int s0 = ((kg * 2)     ^ (m & 7)) << 3;
            const int s1 = ((kg * 2 + 1) ^ (m & 7)) << 3;
            const ush* src = (const ush*)Xv + ((size_t)(b * N_ + n) * 3 + t) * K + kk + kg * 16;
            ush h[16];
            *(uint4*)&h[0] = *(const uint4*)(src);
            *(uint4*)&h[8] = *(const uint4*)(src + 8);
            *(short8v*)&Xh[m][s0] = *(short8v*)&h[0];
            *(short8v*)&Xh[m][s1] = *(short8v*)&h[8];
        }
        __syncthreads();
        #pragma unroll
        for (int kc = 0; kc < 2; ++kc) {
            const int sk = ((kc * 4 + grp) ^ (col & 7)) << 3;
            short8v ah0 = *(const short8v*)&Wh[wo * 32 + col][sk];
            short8v ah1 = *(const short8v*)&Wh[wo * 32 + 16 + col][sk];
            short8v xh0 = *(const short8v*)&Xh[wm * 32 + col][sk];
            short8v xh1 = *(const short8v*)&Xh[wm * 32 + 16 + col][sk];
            acc[0][0] = __builtin_amdgcn_mfma_f32_16x16x32_bf16(ah0, xh0, acc[0][0], 0, 0, 0);
            acc[0][1] = __builtin_amdgcn_mfma_f32_16x16x32_bf16(ah0, xh1, acc[0][1], 0, 0, 0);
            acc[1][0] = __builtin_amdgcn_mfma_f32_16x16x32_bf16(ah1, xh0, acc[1][0], 0, 0, 0);
            acc[1][1] = __builtin_amdgcn_mfma_f32_16x16x32_bf16(ah1, xh1, acc[1][1], 0, 0, 0);
        }
        __syncthreads();
    }
    #pragma unroll
    for (int of = 0; of < 2; ++of) {
        #pragma unroll
        for (int r = 0; r < 4; ++r) {
            const int o = oglob + wo * 32 + of * 16 + grp * 4 + r;
            #pragma unroll
            for (int mf = 0; mf < 2; ++mf) {
                const int mloc = m0 + wm * 32 + mf * 16 + col;
                const size_t idx = ((size_t)b * Ostr + o) * M + mloc;
                float v = acc[of][mf][r];
                if (OMODE == 0) {
                    if (Z) v += Z[idx];
                    Y[idx] = v;
                }
                if (OMODE == 3) Ybf[idx] = f2bf(v);
                if (OMODE == 4) {
                    ush bv = f2bf(v);
                    const int t = mloc >> 11, n = mloc & (N_ - 1);
                    const int h = (o >> 4) & 7, cl = o & 15;
                    const int d = cl * 3 + t;
                    if (o >= 256) {
                        const int kt = n >> 6, hh = (n >> 5) & 1, db = d >> 4;
                        const size_t idx2 = ((size_t)(b * 8 + h) * 192
                                           + (kt * 2 + hh) * 3 + db) * 512
                                          + (((n >> 3) & 3) * 16 + (d & 15)) * 8 + (n & 7);
                        Ybf[idx2] = bv;
                    } else {
                        const int isK = (o >> 7) & 1;
                        const int qg = n >> 4, half = d >> 5;
                        const size_t idx2 = ((size_t)(isK * 16 + b * 8 + h) * 256
                                           + qg * 2 + half) * 512
                                          + (((d >> 3) & 3) * 16 + (n & 15)) * 8 + (d & 7);
                        Ytr[idx2] = bv;
                    }
                }
            }
        }
    }
}

template <int XMODE, int OMODE, bool XBF>
__global__ __launch_bounds__(256) void gemm_kernel2(
    const u32* __restrict__ Wsp, int wstride,
    const void* __restrict__ Xv,
    const float* __restrict__ Z,
    float* __restrict__ Y, ush* __restrict__ Ybf,
    int Ostr, int obase, int K)
{
    __shared__ __align__(16) ush Wh[64][64];
    __shared__ __align__(16) ush Xh[64][64];
    gemm_tile<XMODE, OMODE, XBF>(Wsp, wstride, Xv, K, Z, Y, Ybf, nullptr,
                            blockIdx.z, blockIdx.x * 64,
                            blockIdx.y * 64, obase + blockIdx.y * 64, Ostr,
                            Wh, Xh);
}

// ---------------------------------------------------------------------------
// fused output mix: Y = Wfa*ao (K=128, XMODE0) + Wfb*gbuf (K=256, XMODE1) + Z
// ---------------------------------------------------------------------------
__global__ __launch_bounds__(256) void wm2_kernel(
    const u32* __restrict__ Wfa, const u32* __restrict__ Wfb,
    const ush* __restrict__ ao, const ush* __restrict__ gb,
    const float* __restrict__ Z, float* __restrict__ Y)
{
    __shared__ __align__(16) ush Wh[64][64];
    __shared__ __align__(16) ush Xh[64][64];
    const int M = 3 * N_;
    const int b = blockIdx.z;
    const int m0 = blockIdx.x * 64;
    const int o0 = blockIdx.y * 64;
    const int tid = threadIdx.x;
    const int lane = tid & 63, wv = tid >> 6;
    const int col = lane & 15, grp = lane >> 4;
    const int wo = wv >> 1, wm = wv & 1;

    f32x4 acc[2][2];
    #pragma unroll
    for (int i = 0; i < 2; ++i)
        #pragma unroll
        for (int j = 0; j < 2; ++j) { f32x4 z = {0.f,0.f,0.f,0.f}; acc[i][j] = z; }

    for (int kk = 0; kk < 128; kk += 64) {
        {
            const int o = tid >> 2, kg = tid & 3;
            const u32* src = Wfa + (size_t)(o0 + o) * 128 + kk + kg * 16;
            u32 buf[16];
            #pragma unroll
            for (int j = 0; j < 4; ++j) *(uint4*)&buf[j * 4] = *(const uint4*)(src + j * 4);
            const int s0 = ((kg * 2)     ^ (o & 7)) << 3;
            const int s1 = ((kg * 2 + 1) ^ (o & 7)) << 3;
            short8v h0, h1; unpack_hi(buf, h0, h1);
            *(short8v*)&Wh[o][s0] = h0; *(short8v*)&Wh[o][s1] = h1;
        }
        {
            const int m = lane, kq = wv;
            const int s0 = ((kq * 2)     ^ (m & 7)) << 3;
            const int s1 = ((kq * 2 + 1) ^ (m & 7)) << 3;
            const ush* src = ao + ((size_t)b * 128 + kk + kq * 16) * M + m0 + m;
            ush h[16];
            #pragma unroll
            for (int j = 0; j < 16; ++j) h[j] = src[(size_t)j * M];
            *(short8v*)&Xh[m][s0] = *(short8v*)&h[0];
            *(short8v*)&Xh[m][s1] = *(short8v*)&h[8];
        }
        __syncthreads();
        #pragma unroll
        for (int kc = 0; kc < 2; ++kc) {
            const int sk = ((kc * 4 + grp) ^ (col & 7)) << 3;
            short8v ah0 = *(const short8v*)&Wh[wo * 32 + col][sk];
            short8v ah1 = *(const short8v*)&Wh[wo * 32 + 16 + col][sk];
            short8v xh0 = *(const short8v*)&Xh[wm * 32 + col][sk];
            short8v xh1 = *(const short8v*)&Xh[wm * 32 + 16 + col][sk];
            acc[0][0] = __builtin_amdgcn_mfma_f32_16x16x32_bf16(ah0, xh0, acc[0][0], 0, 0, 0);
            acc[0][1] = __builtin_amdgcn_mfma_f32_16x16x32_bf16(ah0, xh1, acc[0][1], 0, 0, 0);
            acc[1][0] = __builtin_amdgcn_mfma_f32_16x16x32_bf16(ah1, xh0, acc[1][0], 0, 0, 0);
            acc[1][1] = __builtin_amdgcn_mfma_f32_16x16x32_bf16(ah1, xh1, acc[1][1], 0, 0, 0);
        }
        __syncthreads();
    }

    for (int kk = 0; kk < 256; kk += 64) {
        {
            const int o = tid >> 2, kg = tid & 3;
            const u32* src = Wfb + (size_t)(o0 + o) * 256 + kk + kg * 16;
            u32 buf[16];
            #pragma unroll
            for (int j = 0; j < 4; ++j) *(uint4*)&buf[j * 4] = *(const uint4*)(src + j * 4);
            const int s0 = ((kg * 2)     ^ (o & 7)) << 3;
            const int s1 = ((kg * 2 + 1) ^ (o & 7)) << 3;
            short8v h0, h1; unpack_hi(buf, h0, h1);
            *(short8v*)&Wh[o][s0] = h0; *(short8v*)&Wh[o][s1] = h1;
        }
        {
            const int m = tid >> 2, kg = tid & 3;
            const int mg = m0 + m;
            const int n = mg & (N_ - 1), t = mg >> 11;
            const int s0 = ((kg * 2)     ^ (m & 7)) << 3;
            const int s1 = ((kg * 2 + 1) ^ (m & 7)) << 3;
            const ush* src = gb + ((size_t)(b * N_ + n) * 3 + t) * 256 + kk + kg * 16;
            ush h[16];
            *(uint4*)&h[0] = *(const uint4*)(src);
            *(uint4*)&h[8] = *(const uint4*)(src + 8);
            *(short8v*)&Xh[m][s0] = *(short8v*)&h[0];
            *(short8v*)&Xh[m][s1] = *(short8v*)&h[8];
        }
        __syncthreads();
        #pragma unroll
        for (int kc = 0; kc < 2; ++kc) {
            const int sk = ((kc * 4 + grp) ^ (col & 7)) << 3;
            short8v ah0 = *(const short8v*)&Wh[wo * 32 + col][sk];
            short8v ah1 = *(const short8v*)&Wh[wo * 32 + 16 + col][sk];
            short8v xh0 = *(const short8v*)&Xh[wm * 32 + col][sk];
            short8v xh1 = *(const short8v*)&Xh[wm * 32 + 16 + col][sk];
            acc[0][0] = __builtin_amdgcn_mfma_f32_16x16x32_bf16(ah0, xh0, acc[0][0], 0, 0, 0);
            acc[0][1] = __builtin_amdgcn_mfma_f32_16x16x32_bf16(ah0, xh1, acc[0][1], 0, 0, 0);
            acc[1][0] = __builtin_amdgcn_mfma_f32_16x16x32_bf16(ah1, xh0, acc[1][0], 0, 0, 0);
            acc[1][1] = __builtin_amdgcn_mfma_f32_16x16x32_bf16(ah1, xh1, acc[1][1], 0, 0, 0);
        }
        __syncthreads();
    }

    #pragma unroll
    for (int of = 0; of < 2; ++of) {
        #pragma unroll
        for (int r = 0; r < 4; ++r) {
            const int o = o0 + wo * 32 + of * 16 + grp * 4 + r;
            #pragma unroll
            for (int mf = 0; mf < 2; ++mf) {
                const int mloc = m0 + wm * 32 + mf * 16 + col;
                const size_t idx = ((size_t)b * 128 + o) * M + mloc;
                Y[idx] = acc[of][mf][r] + Z[idx];
            }
        }
    }
}

struct QKVArgs {
    const u32* W0; const u32* W1; const u32* W2;
    const ush* X0; const ush* X1; const ush* X2;
};

// fused: qkv projections (blocks 0..1151) + bf16 transpose(s) (blocks 1152..)
__global__ __launch_bounds__(256) void qkv_tr_kernel(QKVArgs A,
        ush* __restrict__ vfm, ush* __restrict__ qktb,
        const ush* __restrict__ ts0, ush* __restrict__ td0,
        const ush* __restrict__ ts1, ush* __restrict__ td1)
{
    __shared__ __align__(16) ush Wh[64][64];
    __shared__ __align__(16) ush Xh[64][64];
    __shared__ ush ttile[32][34];
    const int bx = blockIdx.x;
    if (bx < 1152) {
        const int z = bx / 576, rem = bx % 576;
        const int y = rem / 96, x = rem % 96;
        const int wi = y >> 1;
        const u32* W = wi == 0 ? A.W0 : (wi == 1 ? A.W1 : A.W2);
        const ush* X = wi == 0 ? A.X0 : (wi == 1 ? A.X1 : A.X2);
        gemm_tile<0, 4, true>(W, 128, X, 128, nullptr, nullptr, vfm, qktb,
                        z, x * 64, (y & 1) * 64, y * 64, 384,
                        Wh, Xh);
    } else {
        int i = bx - 1152;
        const int which = i / 1536; i %= 1536;
        const ush* src = which ? ts1 : ts0;
        ush* dst = which ? td1 : td0;
        const int x = i & 63, y = (i >> 6) & 3, z = i >> 8;
        const int b = z / 3, t = z % 3;
        const int n0 = x * 32, c0 = y * 32;
        const int tx = threadIdx.x & 31, ty = threadIdx.x >> 5;
        #pragma unroll
        for (int p = 0; p < 4; ++p) {
            int c = c0 + ty + p * 8;
            ttile[ty + p * 8][tx] = src[((size_t)(b * C_ + c) * 3 + t) * N_ + n0 + tx];
        }
        __syncthreads();
        #pragma unroll
        for (int p = 0; p < 4; ++p) {
            int n = n0 + ty + p * 8;
            dst[((size_t)(b * N_ + n) * 3 + t) * C_ + c0 + tx] = ttile[tx][ty + p * 8];
        }
    }
}

// ---------------------------------------------------------------------------
// barrier-free split-K flash attention, XCD-chunked 1D grid (1024 blocks).
// ---------------------------------------------------------------------------
__global__ __launch_bounds__(256) void attn_mfma_kernel(
    const ush* __restrict__ vfm, const ush* __restrict__ qktb,
    ush* __restrict__ pacc, float* __restrict__ pml)
{
    __shared__ __align__(16) ush Pl[4][2][16][64];   // 16 KB

    const int flat = blockIdx.x;
    const int xcd  = flat & 7;
    const int slot = flat >> 3;          // 0..127
    const int bh   = xcd * 2 + (slot >> 6);   // 0..15
    const int q32  = slot & 63;

    const int tid = threadIdx.x;
    const int lane = tid & 63, wv = tid >> 6;
    const int col = lane & 15, grp = lane >> 4;
    const int c7  = col & 7;
    const int kz  = wv;
    const int ks0 = kz * (N_ / KSPLIT);

    const ush* Qpl = qktb + (size_t)bh * 131072;
    const ush* Kpl = qktb + (size_t)(16 + bh) * 131072;
    const ush* Vpl = vfm  + (size_t)bh * 98304;

    short8v qf[2][2];
    #pragma unroll
    for (int qi = 0; qi < 2; ++qi) {
        const int qg = q32 * 2 + qi;
        qf[qi][0] = *(const short8v*)(Qpl + ((size_t)qg * 2 + 0) * 512 + lane * 8);
        qf[qi][1] = *(const short8v*)(Qpl + ((size_t)qg * 2 + 1) * 512 + lane * 8);
    }

    f32x4 acc[2][3];
    #pragma unroll
    for (int qi = 0; qi < 2; ++qi)
        #pragma unroll
        for (int db = 0; db < 3; ++db) { f32x4 z = {0.f,0.f,0.f,0.f}; acc[qi][db] = z; }
    float m_i[2] = {0.f, 0.f};
    float l_l[2] = {0.f, 0.f};

    const int NT = (N_ / KSPLIT) / 64;   // 8 tiles of 64 keys
    for (int mt = 0; mt < NT; ++mt) {
        const int m0 = ks0 + mt * 64;

        short8v ka[4][2];
        #pragma unroll
        for (int kb = 0; kb < 4; ++kb) {
            const size_t kg = (m0 >> 4) + kb;
            ka[kb][0] = *(const short8v*)(Kpl + (kg * 2 + 0) * 512 + lane * 8);
            ka[kb][1] = *(const short8v*)(Kpl + (kg * 2 + 1) * 512 + lane * 8);
        }
        const int kt = m0 >> 6;
        short8v vf[2][3];
        #pragma unroll
        for (int hh = 0; hh < 2; ++hh)
            #pragma unroll
            for (int db = 0; db < 3; ++db)
                vf[hh][db] = *(const short8v*)(Vpl + (size_t)((kt * 2 + hh) * 3 + db) * 512 + lane * 8);

        f32x4 sf[2][4];
        __builtin_amdgcn_s_setprio(1);
        #pragma unroll
        for (int qi = 0; qi < 2; ++qi)
            #pragma unroll
            for (int kb = 0; kb < 4; ++kb) {
                f32x4 z = {0.f, 0.f, 0.f, 0.f};
                z = __builtin_amdgcn_mfma_f32_16x16x32_bf16(ka[kb][0], qf[qi][0], z, 0, 0, 0);
                z = __builtin_amdgcn_mfma_f32_16x16x32_bf16(ka[kb][1], qf[qi][1], z, 0, 0, 0);
                sf[qi][kb] = z;
            }
        __builtin_amdgcn_s_setprio(0);

        #pragma unroll
        for (int qi = 0; qi < 2; ++qi) {
            float psum = 0.f;
            #pragma unroll
            for (int kb = 0; kb < 4; ++kb) {
                float e0 = __expf(sf[qi][kb][0] - m_i[qi]);
                float e1 = __expf(sf[qi][kb][1] - m_i[qi]);
                float e2 = __expf(sf[qi][kb][2] - m_i[qi]);
                float e3 = __expf(sf[qi][kb][3] - m_i[qi]);
                psum += (e0 + e1) + (e2 + e3);
                u32 r0, r1;
                asm("v_cvt_pk_bf16_f32 %0, %1, %2" : "=v"(r0) : "v"(e0), "v"(e1));
                asm("v_cvt_pk_bf16_f32 %0, %1, %2" : "=v"(r1) : "v"(e2), "v"(e3));
                const int un = (4 * kb + grp) ^ (c7 << 1);
                uint2 pk2; pk2.x = r0; pk2.y = r1;
                *(uint2*)&Pl[wv][qi][col][un << 2] = pk2;
            }
            l_l[qi] += psum;
        }

        __builtin_amdgcn_s_setprio(1);
        #pragma unroll
        for (int qi = 0; qi < 2; ++qi)
            #pragma unroll
            for (int hh = 0; hh < 2; ++hh) {
                const int ur = (8 * hh + 2 * grp) ^ (c7 << 1);
                short8v pf = *(const short8v*)&Pl[wv][qi][col][ur << 2];
                #pragma unroll
                for (int db = 0; db < 3; ++db)
                    acc[qi][db] = __builtin_amdgcn_mfma_f32_16x16x32_bf16(vf[hh][db], pf, acc[qi][db], 0, 0, 0);
            }
        __builtin_amdgcn_s_setprio(0);

        #pragma unroll
        for (int qi = 0; qi < 2; ++qi) {
            float pmax = -1e30f;
            #pragma unroll
            for (int kb = 0; kb < 4; ++kb)
                #pragma unroll
                for (int r = 0; r < 4; ++r) pmax = fmaxf(pmax, sf[qi][kb][r]);
            pmax = fmaxf(pmax, __shfl_xor(pmax, 16, 64));
            pmax = fmaxf(pmax, __shfl_xor(pmax, 32, 64));
            if (!__all(pmax - m_i[qi] <= 8.0f)) {
                float mnew = fmaxf(m_i[qi], pmax);
                float sc = __expf(m_i[qi] - mnew);
                l_l[qi] *= sc;
                #pragma unroll
                for (int db = 0; db < 3; ++db) {
                    acc[qi][db][0] *= sc; acc[qi][db][1] *= sc;
                    acc[qi][db][2] *= sc; acc[qi][db][3] *= sc;
                }
                m_i[qi] = mnew;
            }
        }
    }

    const int ntile = q32 >> 1, qh = q32 & 1;
    const size_t pb = (size_t)(kz * 16 + bh) * 32 + ntile;
    #pragma unroll
    for (int qi = 0; qi < 2; ++qi) {
        float l = l_l[qi];
        l += __shfl_xor(l, 16, 64);
        l += __shfl_xor(l, 32, 64);
        const int q = qh * 32 + qi * 16 + col;
        #pragma unroll
        for (int db = 0; db < 3; ++db)
            #pragma unroll
            for (int r = 0; r < 4; ++r) {
                int d = db * 16 + grp * 4 + r;
                pacc[pb * 3072 + d * 64 + q] = f2bf(acc[qi][db][r]);
            }
        if (grp == 0) {
            pml[pb * 128 + q]      = m_i[qi];
            pml[pb * 128 + 64 + q] = l;
        }
    }
}

// ---------------------------------------------------------------------------
// fused: split-K reduce (blocks 0..511) + graph attention (blocks 512..4607)
// ---------------------------------------------------------------------------
__global__ __launch_bounds__(256) void reduce_graph_kernel(
    const ush* __restrict__ pacc, const float* __restrict__ pml,
    ush* __restrict__ ao,
    const ush* __restrict__ tq, const ush* __restrict__ tv,
    const int* __restrict__ idx, ush* __restrict__ gbuf)
{
    __shared__ float centerf[384];
    __shared__ ush nbr_l[16][384];
    __shared__ float sd[16];
    __shared__ int nbr_i[16];
    const int tid = threadIdx.x;

    if (blockIdx.x < 512) {
        // ============ split-K reduce ============
        const int nt = blockIdx.x & 31, bh = blockIdx.x >> 5;
        const int b = bh >> 3, h = bh & 7;
        const int q = tid & 63, dg = tid >> 6;

        size_t pb[KSPLIT];
        float m[KSPLIT], l[KSPLIT];
        #pragma unroll
        for (int kz = 0; kz < KSPLIT; ++kz) {
            pb[kz] = (size_t)(kz * 16 + bh) * 32 + nt;
            m[kz] = pml[pb[kz] * 128 + q];
            l[kz] = pml[pb[kz] * 128 + 64 + q];
        }
        float ms = -1e30f;
        #pragma unroll
        for (int kz = 0; kz < KSPLIT; ++kz) ms = fmaxf(ms, m[kz]);
        float w[KSPLIT], ls = 0.f;
        #pragma unroll
        for (int kz = 0; kz < KSPLIT; ++kz) { w[kz] = __expf(m[kz] - ms); ls += l[kz] * w[kz]; }
        const float inv = 1.f / ls;

        const size_t hb = ((size_t)(b * C_ + h * 16)) * 3 * N_;
        #pragma unroll
        for (int j = 0; j < 12; ++j) {
            int d = dg * 12 + j;
            float o = 0.f;
            #pragma unroll
            for (int kz = 0; kz < KSPLIT; ++kz)
                o += bf2f(pacc[pb[kz] * 3072 + d * 64 + q]) * w[kz];
            ao[hb + (size_t)d * N_ + nt * 64 + q] = f2bf(o * inv);
        }
    } else {
        // ============ graph attention ============
        const int j = blockIdx.x - 512;
        const int b = j >> 11, n = j & 2047;
        const ush* qrow = tq + (size_t)(b * N_ + n) * 384;
        for (int e = tid; e < 384; e += 256) centerf[e] = bf2f(qrow[e]);
        if (tid < 16) nbr_i[tid] = idx[(size_t)(b * N_ + n) * 16 + tid];
        __syncthreads();

        const int lane = tid & 63, wv = tid >> 6;
        for (int kk = 0; kk < 4; ++kk) {
            int k = wv * 4 + kk;
            const u32* vrow = (const u32*)(tv + ((size_t)b * N_ + nbr_i[k]) * 384);
            float p = 0.f;
            #pragma unroll
            for (int jj = 0; jj < 3; ++jj) {
                int e2 = lane + jj * 64;
                u32 v2 = vrow[e2];
                ((u32*)nbr_l[k])[e2] = v2;
                p += centerf[e2 * 2]     * bf2f((ush)(v2 & 0xffff))
                   + centerf[e2 * 2 + 1] * bf2f((ush)(v2 >> 16));
            }
            #pragma unroll
            for (int off = 32; off; off >>= 1) p += __shfl_down(p, off, 64);
            if (lane == 0) sd[k] = p * 0.05103103630798288f;
        }
        __syncthreads();

        float mx = -1e30f;
        #pragma unroll
        for (int k = 0; k < 16; ++k) mx = fmaxf(mx, sd[k]);
        float a[16]; float ssum = 0.f;
        #pragma unroll
        for (int k = 0; k < 16; ++k) { a[k] = __expf(sd[k] - mx); ssum += a[k]; }
        float inv = 1.f / ssum;

        for (int e = tid; e < 384; e += 256) {
            float accv = 0.f;
            #pragma unroll
            for (int k = 0; k < 16; ++k)
                accv += a[k] * bf2f(nbr_l[k][e]);
            accv *= inv;
            float ce = centerf[e];
            int t = e >> 7, c = e & 127;
            size_t gb = ((size_t)(b * N_ + n) * 3 + t) * 256;
            gbuf[gb + c]       = f2bf(accv - ce);
            gbuf[gb + 128 + c] = f2bf(ce);
        }
    }
}

// ---------------------------------------------------------------------------
// vn_leaky: reads h1hd combined buffer (x = rows 0..511, d = rows 512..1023)
// ---------------------------------------------------------------------------
__global__ __launch_bounds__(256) void leaky_kernel(const ush* __restrict__ h1hd,
                                                    ush* __restrict__ y)
{
    size_t p = (size_t)blockIdx.x * 256 + threadIdx.x;
    size_t bh = p / N_, n = p % N_;
    size_t b = bh / HID_, hid = bh % HID_;
    size_t xb = ((size_t)(b * 1024 + hid)) * 3 * N_ + n;
    size_t db = ((size_t)(b * 1024 + 512 + hid)) * 3 * N_ + n;
    float x0 = bf2f(h1hd[xb]), x1 = bf2f(h1hd[xb + N_]), x2 = bf2f(h1hd[xb + 2 * N_]);
    float d0 = bf2f(h1hd[db]), d1 = bf2f(h1hd[db + N_]), d2 = bf2f(h1hd[db + 2 * N_]);
    float dot = x0 * d0 + x1 * d1 + x2 * d2;
    float dsq = d0 * d0 + d1 * d1 + d2 * d2;
    float f = dot / (dsq + EPS_);
    bool pos = dot >= 0.f;
    float y0 = pos ? x0 : x0 - f * d0;
    float y1 = pos ? x1 : x1 - f * d1;
    float y2 = pos ? x2 : x2 - f * d2;
    size_t base = bh * 3 * N_ + n;
    y[base]          = f2bf(NS_ * x0 + (1.f - NS_) * y0);
    y[base + N_]     = f2bf(NS_ * x1 + (1.f - NS_) * y1);
    y[base + 2 * N_] = f2bf(NS_ * x2 + (1.f - NS_) * y2);
}

// ---------------------------------------------------------------------------
extern "C" void kernel_launch(void* const* d_in, const int* in_sizes, int n_in,
                              void* d_out, int out_size, void* d_ws, size_t ws_size,
                              hipStream_t stream)
{
    const float* q_in = (const float*)d_in[0];
    const float* v_in = (const float*)d_in[1];
    const int*   idx_s = (const int*)d_in[4];
    const int*   idx_c = (const int*)d_in[5];
    const float* g1 = (const float*)d_in[6];
    const float* b1 = (const float*)d_in[7];
    const float* g2 = (const float*)d_in[8];
    const float* b2 = (const float*)d_in[9];
    const float* gq = (const float*)d_in[10];
    const float* bq = (const float*)d_in[11];
    const float* gv = (const float*)d_in[12];
    const float* bv = (const float*)d_in[13];
    float* out = (float*)d_out;
    float* ws  = (float*)d_ws;

    const size_t S1 = (size_t)B_ * C_ * 3 * N_; // 1572864 elems
    ush*   gbuf_b= (ush*)(ws);         // 0 (6.3MB; live reduce_graph -> wm2)
    ush*   nx_b  = (ush*)(ws + 2*S1);  // 2 (half)
    ush*   nv_b  = (ush*)(ws + 3*S1);  // 3 (half)
    ush*   vfm   = (ush*)(ws + 4*S1);  // 4: 3MB
    ush*   qktb  = (ush*)(ws + 5*S1) + S1;  // 5.5-6.84: 8.4MB
    ush*   ao_b  = (ush*)(ws + 7*S1);  // 7 (half)
    float* qa    = ws + 12*S1;         // 12
    float* qb    = ws + 13*S1;         // 13
    ush*   t1_b  = (ush*)(ws + 14*S1); // 14 (half)
    ush*   t2_b  = (ush*)(ws + 15*S1); // 15 (half)
    u32*   wsp   = (u32*)(ws + 16*S1); // 16+
    // split-K attention partials (attn->reduce window only; KSPLIT=4: 12.6MB)
    ush*   pacc  = (ush*)(ws + 8*S1);  // 8-9
    float* pml   = (float*)(ws + 2*S1);// 2 (attn after qkv consumed nx_b)
    // phase C aliases (all bf16):
    ush*   h1hd  = (ush*)(ws + 8*S1);  // 8-11: (B,1024,M) bf16 = 25.2MB (pacc dead)
    ush*   h1_b2 = (ush*)(ws + 14*S1); // 14-15 (t1/t2 dead): (B,512,M) bf16

    // weight planes: 8 split-converted + Dfused + 4 fused Wfa/Wfb
    const int wn[8]   = {16384,16384,16384, 16384,16384,16384, 65536,65536};
    const int wsrc[8] = {14,15,16, 20,21,22, 26,28};
    u32* wd[8];
    {
        int off = 0;
        for (int i = 0; i < 8; ++i) { wd[i] = wsp + off; off += wn[i]; }
    }
    u32 *Wq_s = wd[0], *Wk_s = wd[1], *Wv_s = wd[2];
    u32 *Wq_c = wd[3], *Wk_c = wd[4], *Wv_c = wd[5];
    u32 *W1D  = wd[6];                 // 1024x128: rows 0-511 = W1, 512-1023 = Dfused
    u32 *Dfused = wsp + 98304 + 65536; // rows 512-1023 of W1D
    u32 *W2   = wsp + 229376;
    u32* Wfa_s = wsp + 491520;
    u32* Wfb_s = Wfa_s + 16384;
    u32* Wfa_c = Wfb_s + 32768;
    u32* Wfb_c = Wfa_c + 16384;

    {
        SetupArgs a{};
        for (int i = 0; i < 8; ++i) {
            a.src[i] = (const float*)d_in[wsrc[i]];
            a.n[i]   = wn[i];
            a.scale[i] = 1.f;
        }
        a.dst[0] = Wq_s; a.dst[1] = Wk_s; a.dst[2] = Wv_s;
        a.dst[3] = Wq_c; a.dst[4] = Wk_c; a.dst[5] = Wv_c;
        a.dst[6] = W1D;  a.dst[7] = W2;
        a.scale[0] = 0.14433756729740643f;  // Wq_s: fold 1/sqrt(48)
        a.scale[3] = 0.14433756729740643f;  // Wq_c
        a.Wm[0] = (const float*)d_in[19]; a.Wo[0] = (const float*)d_in[17]; a.We[0] = (const float*)d_in[18];
        a.Wm[1] = (const float*)d_in[25]; a.Wo[1] = (const float*)d_in[23]; a.We[1] = (const float*)d_in[24];
        a.Wfa[0] = Wfa_s; a.Wfb[0] = Wfb_s;
        a.Wfa[1] = Wfa_c; a.Wfb[1] = Wfb_c;
        a.qkz = (uint4*)qktb;
        setup_kernel<<<dim3(8192 + 384 + 1024), 256, 0, stream>>>(a);
    }
    dfuse_kernel<<<dim3(16), 256, 0, stream>>>((const float*)d_in[27],
                                               (const float*)d_in[26], Dfused);

    dim3 gwm(96, 2, B_);

    // ---- Phase A: self attention block ----
    {
        LNArgs la{};
        la.x[0] = q_in; la.g[0] = g1; la.bt[0] = b1; la.ysp[0] = nx_b;
        ln_kernel<<<dim3(64, B_, 1), 256, 0, stream>>>(la);
    }
    {
        QKVArgs A{Wq_s, Wk_s, Wv_s, nx_b, nx_b, nx_b};
        qkv_tr_kernel<<<dim3(1152 + 1536), 256, 0, stream>>>(A, vfm, qktb, nx_b, t1_b, nullptr, nullptr);
    }
    attn_mfma_kernel<<<dim3(1024), 256, 0, stream>>>(vfm, qktb, pacc, pml);
    reduce_graph_kernel<<<dim3(512 + 4096), 256, 0, stream>>>(pacc, pml, ao_b, t1_b, t1_b, idx_s, gbuf_b);
    wm2_kernel<<<gwm, 256, 0, stream>>>(Wfa_s, Wfb_s, ao_b, gbuf_b, q_in, qa);

    // ---- Phase B: cross attention block ----
    {
        LNArgs la{};
        la.x[0] = qa;   la.g[0] = gq; la.bt[0] = bq; la.ysp[0] = nx_b;
        la.x[1] = v_in; la.g[1] = gv; la.bt[1] = bv; la.ysp[1] = nv_b;
        ln_kernel<<<dim3(64, B_, 2), 256, 0, stream>>>(la);
    }
    {
        QKVArgs A{Wq_c, Wk_c, Wv_c, nx_b, nv_b, nv_b};
        qkv_tr_kernel<<<dim3(1152 + 3072), 256, 0, stream>>>(A, vfm, qktb, nx_b, t1_b, nv_b, t2_b);
    }
    attn_mfma_kernel<<<dim3(1024), 256, 0, stream>>>(vfm, qktb, pacc, pml);
    reduce_graph_kernel<<<dim3(512 + 4096), 256, 0, stream>>>(pacc, pml, ao_b, t1_b, t2_b, idx_c, gbuf_b);
    wm2_kernel<<<gwm, 256, 0, stream>>>(Wfa_c, Wfb_c, ao_b, gbuf_b, qa, qb);

    // ---- Phase C: vector MLP (fused W1+Dfused single GEMM, K=128) ----
    {
        LNArgs la{};
        la.x[0] = qb; la.g[0] = g2; la.bt[0] = b2; la.ysp[0] = nx_b;
        ln_kernel<<<dim3(64, B_, 1), 256, 0, stream>>>(la);
    }
    gemm_kernel2<0,3,true><<<dim3(96, 16, B_), 256, 0, stream>>>(W1D, 128, nx_b, nullptr, nullptr, h1hd, 1024, 0, 128);
    leaky_kernel<<<dim3((B_ * HID_ * N_) / 256), 256, 0, stream>>>(h1hd, h1_b2);
    gemm_kernel2<0,0,true><<<dim3(96, 2, B_), 256, 0, stream>>>(W2, 512, h1_b2, qb, out, nullptr, 128, 0, 512);
}

// Round 22
// 235.100 us; speedup vs baseline: 1.4871x; 1.4871x over previous
//
#include <hip/hip_runtime.h>
#include <math.h>

#define B_    2
#define C_    128
#define N_    2048
#define HID_  512
#define HEADS_ 8
#define EPS_  1e-6f
#define NS_   0.2f
#define KSPLIT 4

typedef __attribute__((ext_vector_type(8))) short short8v;  // 8 bf16
typedef __attribute__((ext_vector_type(4))) float f32x4;
typedef unsigned short ush;
typedef unsigned int u32;

__device__ inline ush f2bf(float f) {
    unsigned u = __float_as_uint(f);
    u += 0x7FFF + ((u >> 16) & 1);          // round-to-nearest-even
    return (ush)(u >> 16);
}
__device__ inline float bf2f(ush u) { return __uint_as_float((u32)u << 16); }

// pack float -> (hi bf16 << 16) | lo bf16
__device__ inline u32 splitpack(float x) {
    ush hi = f2bf(x);
    float hf = __uint_as_float((u32)hi << 16);
    ush lo = f2bf(x - hf);
    return ((u32)hi << 16) | (u32)lo;
}

__device__ inline void unpack_hi(const u32* buf, short8v& h0, short8v& h1) {
    ush h[16];
    #pragma unroll
    for (int j = 0; j < 16; ++j) h[j] = (ush)(buf[j] >> 16);
    h0 = *(short8v*)&h[0]; h1 = *(short8v*)&h[8];
}

// ---------------------------------------------------------------------------
// vec_layernorm, z-indexed multi-input, single global read pass (registers)
// ---------------------------------------------------------------------------
struct LNArgs {
    const float* x[2]; const float* g[2]; const float* bt[2]; ush* ysp[2];
};
__global__ __launch_bounds__(256) void ln_kernel(LNArgs a)
{
    __shared__ float red1[8][32];
    __shared__ float red2[8][32];
    const int s = blockIdx.z;
    const float* x = a.x[s];
    const float* gma = a.g[s];
    const float* bta = a.bt[s];
    ush* ysp = a.ysp[s];

    const int b  = blockIdx.y;
    const int n0 = blockIdx.x * 32;
    const int nn = threadIdx.x & 31;
    const int cg = threadIdx.x >> 5;

    float xr0[16], xr1[16], xr2[16], nrr[16];
    float s1 = 0.f, s2 = 0.f;
    #pragma unroll
    for (int it = 0; it < 16; ++it) {
        int c = it * 8 + cg;
        size_t base = ((size_t)(b * C_ + c) * 3) * N_ + n0 + nn;
        float x0 = x[base], x1 = x[base + N_], x2 = x[base + 2 * N_];
        float nr = sqrtf(x0 * x0 + x1 * x1 + x2 * x2 + EPS_);
        xr0[it] = x0; xr1[it] = x1; xr2[it] = x2; nrr[it] = nr;
        s1 += nr; s2 += nr * nr;
    }
    red1[cg][nn] = s1; red2[cg][nn] = s2;
    __syncthreads();
    float S1 = 0.f, S2 = 0.f;
    #pragma unroll
    for (int g = 0; g < 8; ++g) { S1 += red1[g][nn]; S2 += red2[g][nn]; }
    float mu   = S1 * (1.f / 128.f);
    float var  = S2 * (1.f / 128.f) - mu * mu;
    float rstd = rsqrtf(var + EPS_);

    #pragma unroll
    for (int it = 0; it < 16; ++it) {
        int c = it * 8 + cg;
        float nr = nrr[it];
        float ln = (nr - mu) * rstd * gma[c] + bta[c];
        float sc = ln / (nr + EPS_);
        size_t base = ((size_t)(b * C_ + c) * 3) * N_ + n0 + nn;
        ysp[base]          = f2bf(xr0[it] * sc);
        ysp[base + N_]     = f2bf(xr1[it] * sc);
        ysp[base + 2 * N_] = f2bf(xr2[it] * sc);
    }
}

// ---------------------------------------------------------------------------
// fused setup (NO LDS -> full occupancy for the memory-bound blocks):
//   blocks [0, 8192):    8 weight split-conversions (w = bx>>10)
//   blocks [8192, 8576): output-mix weight products Wfa/Wfb
//   blocks [8576, 9600): qktb zeroing
// ---------------------------------------------------------------------------
struct SetupArgs {
    const float* src[8]; u32* dst[8]; int n[8]; float scale[8];
    const float* Wm[2]; const float* Wo[2]; const float* We[2];
    u32* Wfa[2]; u32* Wfb[2];
    uint4* qkz;
};
__global__ __launch_bounds__(256) void setup_kernel(SetupArgs a)
{
    const int bx = blockIdx.x;
    if (bx < 8192) {
        const int w = bx >> 10;
        const int i = (bx & 1023) * 256 + threadIdx.x;
        if (i < a.n[w]) a.dst[w][i] = splitpack(a.src[w][i] * a.scale[w]);
    } else if (bx < 8576) {
        const int tg = (bx - 8192) * 256 + threadIdx.x;   // 0..98303
        const int p = tg / 49152;
        const int rem = tg % 49152;
        if (rem < 16384) {
            const int o = rem >> 7, k = rem & 127;
            const float* Wm = a.Wm[p];
            const float* Wo = a.Wo[p];
            float acc = 0.f;
            #pragma unroll 4
            for (int c = 0; c < 128; ++c)
                acc += Wm[o * 256 + c] * Wo[c * 128 + k];
            a.Wfa[p][o * 128 + k] = splitpack(acc);
        } else {
            const int r2 = rem - 16384;
            const int o = r2 >> 8, k = r2 & 255;
            const float* Wm = a.Wm[p];
            const float* We = a.We[p];
            float acc = 0.f;
            #pragma unroll 4
            for (int c = 0; c < 128; ++c)
                acc += Wm[o * 256 + 128 + c] * We[c * 256 + k];
            a.Wfb[p][o * 256 + k] = splitpack(acc);
        }
    } else {
        // zero qktb (524288 uint4 = 8.4MB); 1024 blocks x 512 uint4
        const size_t i0 = ((size_t)(bx - 8576) * 256 + threadIdx.x) * 2;
        uint4 z = {0, 0, 0, 0};
        a.qkz[i0]     = z;
        a.qkz[i0 + 1] = z;
    }
}

// ---------------------------------------------------------------------------
// Dfused = Dact*W1 via split-4 partial dots: maximal TLP (262144 threads),
// 128-long dots like the proven wfuse pattern. Combine pass sums in fixed
// order and splitpacks.
// ---------------------------------------------------------------------------
__global__ __launch_bounds__(256) void dfuse_part_kernel(
    const float* __restrict__ DactF, const float* __restrict__ W1F,
    float* __restrict__ dtmp)
{
    const int t = blockIdx.x * 256 + threadIdx.x;   // 0..262143
    const int oi = t >> 2, q = t & 3;
    const int o = oi >> 7, k = oi & 127;
    const int c0 = q * 128;
    float acc = 0.f;
    #pragma unroll 4
    for (int c = 0; c < 128; ++c)
        acc += DactF[o * 512 + c0 + c] * W1F[(c0 + c) * 128 + k];
    dtmp[t] = acc;
}

__global__ __launch_bounds__(256) void dfuse_comb_kernel(
    const float* __restrict__ dtmp, u32* __restrict__ Dfused)
{
    const int oi = blockIdx.x * 256 + threadIdx.x;  // 0..65535
    float s = ((dtmp[oi * 4] + dtmp[oi * 4 + 1]) + dtmp[oi * 4 + 2]) + dtmp[oi * 4 + 3];
    Dfused[oi] = splitpack(s);
}

// ---------------------------------------------------------------------------
// bf16 MFMA GEMM core (hi-only). XBF: X input is bf16 ush (else split u32).
// XMODE 0: X[(b*K + c)*M + m]   XMODE 1: X[((b*N+n)*3+t)*K + c], m = t*N+n
// OMODE 0: fp32(+Z)  3: bf16 Ybf  4: qkv fragment-major
// ---------------------------------------------------------------------------
template <int XMODE, int OMODE, bool XBF>
__device__ __forceinline__ void gemm_tile(
    const u32* __restrict__ Wsp, int wstride,
    const void* __restrict__ Xv, int K,
    const float* __restrict__ Z, float* __restrict__ Y,
    ush* __restrict__ Ybf, ush* __restrict__ Ytr,
    int b, int m0, int o0loc, int oglob, int Ostr,
    ush (*Wh)[64], ush (*Xh)[64])
{
    const int M = 3 * N_;
    const int tid = threadIdx.x;
    const int lane = tid & 63, wv = tid >> 6;
    const int col = lane & 15, grp = lane >> 4;
    const int wo = wv >> 1, wm = wv & 1;

    f32x4 acc[2][2];
    #pragma unroll
    for (int i = 0; i < 2; ++i)
        #pragma unroll
        for (int j = 0; j < 2; ++j) { f32x4 z = {0.f,0.f,0.f,0.f}; acc[i][j] = z; }

    for (int kk = 0; kk < K; kk += 64) {
        {
            const int o = tid >> 2, kg = tid & 3;
            const u32* src = Wsp + (size_t)(o0loc + o) * wstride + kk + kg * 16;
            u32 buf[16];
            #pragma unroll
            for (int j = 0; j < 4; ++j) *(uint4*)&buf[j * 4] = *(const uint4*)(src + j * 4);
            const int s0 = ((kg * 2)     ^ (o & 7)) << 3;
            const int s1 = ((kg * 2 + 1) ^ (o & 7)) << 3;
            short8v h0, h1; unpack_hi(buf, h0, h1);
            *(short8v*)&Wh[o][s0] = h0; *(short8v*)&Wh[o][s1] = h1;
        }
        if (XMODE == 0) {
            const int m = lane, kq = wv;
            const int s0 = ((kq * 2)     ^ (m & 7)) << 3;
            const int s1 = ((kq * 2 + 1) ^ (m & 7)) << 3;
            if (XBF) {
                const ush* src = (const ush*)Xv + ((size_t)b * K + kk + kq * 16) * M + m0 + m;
                ush h[16];
                #pragma unroll
                for (int j = 0; j < 16; ++j) h[j] = src[(size_t)j * M];
                *(short8v*)&Xh[m][s0] = *(short8v*)&h[0];
                *(short8v*)&Xh[m][s1] = *(short8v*)&h[8];
            } else {
                const u32* src = (const u32*)Xv + ((size_t)b * K + kk + kq * 16) * M + m0 + m;
                u32 buf[16];
                #pragma unroll
                for (int j = 0; j < 16; ++j) buf[j] = src[(size_t)j * M];
                short8v h0, h1; unpack_hi(buf, h0, h1);
                *(short8v*)&Xh[m][s0] = h0; *(short8v*)&Xh[m][s1] = h1;
            }
        } else {
            const int m = tid >> 2, kg = tid & 3;
            const int mg = m0 + m;
            const int n = mg & (N_ - 1), t = mg >> 11;
            const int s0 = ((kg * 2)     ^ (m & 7)) << 3;
            const int s1 = ((kg * 2 + 1) ^ (m & 7)) << 3;
            const ush* src = (const ush*)Xv + ((size_t)(b * N_ + n) * 3 + t) * K + kk + kg * 16;
            ush h[16];
            *(uint4*)&h[0] = *(const uint4*)(src);
            *(uint4*)&h[8] = *(const uint4*)(src + 8);
            *(short8v*)&Xh[m][s0] = *(short8v*)&h[0];
            *(short8v*)&Xh[m][s1] = *(short8v*)&h[8];
        }
        __syncthreads();
        #pragma unroll
        for (int kc = 0; kc < 2; ++kc) {
            const int sk = ((kc * 4 + grp) ^ (col & 7)) << 3;
            short8v ah0 = *(const short8v*)&Wh[wo * 32 + col][sk];
            short8v ah1 = *(const short8v*)&Wh[wo * 32 + 16 + col][sk];
            short8v xh0 = *(const short8v*)&Xh[wm * 32 + col][sk];
            short8v xh1 = *(const short8v*)&Xh[wm * 32 + 16 + col][sk];
            acc[0][0] = __builtin_amdgcn_mfma_f32_16x16x32_bf16(ah0, xh0, acc[0][0], 0, 0, 0);
            acc[0][1] = __builtin_amdgcn_mfma_f32_16x16x32_bf16(ah0, xh1, acc[0][1], 0, 0, 0);
            acc[1][0] = __builtin_amdgcn_mfma_f32_16x16x32_bf16(ah1, xh0, acc[1][0], 0, 0, 0);
            acc[1][1] = __builtin_amdgcn_mfma_f32_16x16x32_bf16(ah1, xh1, acc[1][1], 0, 0, 0);
        }
        __syncthreads();
    }
    #pragma unroll
    for (int of = 0; of < 2; ++of) {
        #pragma unroll
        for (int r = 0; r < 4; ++r) {
            const int o = oglob + wo * 32 + of * 16 + grp * 4 + r;
            #pragma unroll
            for (int mf = 0; mf < 2; ++mf) {
                const int mloc = m0 + wm * 32 + mf * 16 + col;
                const size_t idx = ((size_t)b * Ostr + o) * M + mloc;
                float v = acc[of][mf][r];
                if (OMODE == 0) {
                    if (Z) v += Z[idx];
                    Y[idx] = v;
                }
                if (OMODE == 3) Ybf[idx] = f2bf(v);
                if (OMODE == 4) {
                    ush bv = f2bf(v);
                    const int t = mloc >> 11, n = mloc & (N_ - 1);
                    const int h = (o >> 4) & 7, cl = o & 15;
                    const int d = cl * 3 + t;
                    if (o >= 256) {
                        const int kt = n >> 6, hh = (n >> 5) & 1, db = d >> 4;
                        const size_t idx2 = ((size_t)(b * 8 + h) * 192
                                           + (kt * 2 + hh) * 3 + db) * 512
                                          + (((n >> 3) & 3) * 16 + (d & 15)) * 8 + (n & 7);
                        Ybf[idx2] = bv;
                    } else {
                        const int isK = (o >> 7) & 1;
                        const int qg = n >> 4, half = d >> 5;
                        const size_t idx2 = ((size_t)(isK * 16 + b * 8 + h) * 256
                                           + qg * 2 + half) * 512
                                          + (((d >> 3) & 3) * 16 + (n & 15)) * 8 + (d & 7);
                        Ytr[idx2] = bv;
                    }
                }
            }
        }
    }
}

template <int XMODE, int OMODE, bool XBF>
__global__ __launch_bounds__(256) void gemm_kernel2(
    const u32* __restrict__ Wsp, int wstride,
    const void* __restrict__ Xv,
    const float* __restrict__ Z,
    float* __restrict__ Y, ush* __restrict__ Ybf,
    int Ostr, int obase, int K)
{
    __shared__ __align__(16) ush Wh[64][64];
    __shared__ __align__(16) ush Xh[64][64];
    gemm_tile<XMODE, OMODE, XBF>(Wsp, wstride, Xv, K, Z, Y, Ybf, nullptr,
                            blockIdx.z, blockIdx.x * 64,
                            blockIdx.y * 64, obase + blockIdx.y * 64, Ostr,
                            Wh, Xh);
}

// ---------------------------------------------------------------------------
// fused output mix: Y = Wfa*ao (K=128, XMODE0) + Wfb*gbuf (K=256, XMODE1) + Z
// ---------------------------------------------------------------------------
__global__ __launch_bounds__(256) void wm2_kernel(
    const u32* __restrict__ Wfa, const u32* __restrict__ Wfb,
    const ush* __restrict__ ao, const ush* __restrict__ gb,
    const float* __restrict__ Z, float* __restrict__ Y)
{
    __shared__ __align__(16) ush Wh[64][64];
    __shared__ __align__(16) ush Xh[64][64];
    const int M = 3 * N_;
    const int b = blockIdx.z;
    const int m0 = blockIdx.x * 64;
    const int o0 = blockIdx.y * 64;
    const int tid = threadIdx.x;
    const int lane = tid & 63, wv = tid >> 6;
    const int col = lane & 15, grp = lane >> 4;
    const int wo = wv >> 1, wm = wv & 1;

    f32x4 acc[2][2];
    #pragma unroll
    for (int i = 0; i < 2; ++i)
        #pragma unroll
        for (int j = 0; j < 2; ++j) { f32x4 z = {0.f,0.f,0.f,0.f}; acc[i][j] = z; }

    for (int kk = 0; kk < 128; kk += 64) {
        {
            const int o = tid >> 2, kg = tid & 3;
            const u32* src = Wfa + (size_t)(o0 + o) * 128 + kk + kg * 16;
            u32 buf[16];
            #pragma unroll
            for (int j = 0; j < 4; ++j) *(uint4*)&buf[j * 4] = *(const uint4*)(src + j * 4);
            const int s0 = ((kg * 2)     ^ (o & 7)) << 3;
            const int s1 = ((kg * 2 + 1) ^ (o & 7)) << 3;
            short8v h0, h1; unpack_hi(buf, h0, h1);
            *(short8v*)&Wh[o][s0] = h0; *(short8v*)&Wh[o][s1] = h1;
        }
        {
            const int m = lane, kq = wv;
            const int s0 = ((kq * 2)     ^ (m & 7)) << 3;
            const int s1 = ((kq * 2 + 1) ^ (m & 7)) << 3;
            const ush* src = ao + ((size_t)b * 128 + kk + kq * 16) * M + m0 + m;
            ush h[16];
            #pragma unroll
            for (int j = 0; j < 16; ++j) h[j] = src[(size_t)j * M];
            *(short8v*)&Xh[m][s0] = *(short8v*)&h[0];
            *(short8v*)&Xh[m][s1] = *(short8v*)&h[8];
        }
        __syncthreads();
        #pragma unroll
        for (int kc = 0; kc < 2; ++kc) {
            const int sk = ((kc * 4 + grp) ^ (col & 7)) << 3;
            short8v ah0 = *(const short8v*)&Wh[wo * 32 + col][sk];
            short8v ah1 = *(const short8v*)&Wh[wo * 32 + 16 + col][sk];
            short8v xh0 = *(const short8v*)&Xh[wm * 32 + col][sk];
            short8v xh1 = *(const short8v*)&Xh[wm * 32 + 16 + col][sk];
            acc[0][0] = __builtin_amdgcn_mfma_f32_16x16x32_bf16(ah0, xh0, acc[0][0], 0, 0, 0);
            acc[0][1] = __builtin_amdgcn_mfma_f32_16x16x32_bf16(ah0, xh1, acc[0][1], 0, 0, 0);
            acc[1][0] = __builtin_amdgcn_mfma_f32_16x16x32_bf16(ah1, xh0, acc[1][0], 0, 0, 0);
            acc[1][1] = __builtin_amdgcn_mfma_f32_16x16x32_bf16(ah1, xh1, acc[1][1], 0, 0, 0);
        }
        __syncthreads();
    }

    for (int kk = 0; kk < 256; kk += 64) {
        {
            const int o = tid >> 2, kg = tid & 3;
            const u32* src = Wfb + (size_t)(o0 + o) * 256 + kk + kg * 16;
            u32 buf[16];
            #pragma unroll
            for (int j = 0; j < 4; ++j) *(uint4*)&buf[j * 4] = *(const uint4*)(src + j * 4);
            const int s0 = ((kg * 2)     ^ (o & 7)) << 3;
            const int s1 = ((kg * 2 + 1) ^ (o & 7)) << 3;
            short8v h0, h1; unpack_hi(buf, h0, h1);
            *(short8v*)&Wh[o][s0] = h0; *(short8v*)&Wh[o][s1] = h1;
        }
        {
            const int m = tid >> 2, kg = tid & 3;
            const int mg = m0 + m;
            const int n = mg & (N_ - 1), t = mg >> 11;
            const int s0 = ((kg * 2)     ^ (m & 7)) << 3;
            const int s1 = ((kg * 2 + 1) ^ (m & 7)) << 3;
            const ush* src = gb + ((size_t)(b * N_ + n) * 3 + t) * 256 + kk + kg * 16;
            ush h[16];
            *(uint4*)&h[0] = *(const uint4*)(src);
            *(uint4*)&h[8] = *(const uint4*)(src + 8);
            *(short8v*)&Xh[m][s0] = *(short8v*)&h[0];
            *(short8v*)&Xh[m][s1] = *(short8v*)&h[8];
        }
        __syncthreads();
        #pragma unroll
        for (int kc = 0; kc < 2; ++kc) {
            const int sk = ((kc * 4 + grp) ^ (col & 7)) << 3;
            short8v ah0 = *(const short8v*)&Wh[wo * 32 + col][sk];
            short8v ah1 = *(const short8v*)&Wh[wo * 32 + 16 + col][sk];
            short8v xh0 = *(const short8v*)&Xh[wm * 32 + col][sk];
            short8v xh1 = *(const short8v*)&Xh[wm * 32 + 16 + col][sk];
            acc[0][0] = __builtin_amdgcn_mfma_f32_16x16x32_bf16(ah0, xh0, acc[0][0], 0, 0, 0);
            acc[0][1] = __builtin_amdgcn_mfma_f32_16x16x32_bf16(ah0, xh1, acc[0][1], 0, 0, 0);
            acc[1][0] = __builtin_amdgcn_mfma_f32_16x16x32_bf16(ah1, xh0, acc[1][0], 0, 0, 0);
            acc[1][1] = __builtin_amdgcn_mfma_f32_16x16x32_bf16(ah1, xh1, acc[1][1], 0, 0, 0);
        }
        __syncthreads();
    }

    #pragma unroll
    for (int of = 0; of < 2; ++of) {
        #pragma unroll
        for (int r = 0; r < 4; ++r) {
            const int o = o0 + wo * 32 + of * 16 + grp * 4 + r;
            #pragma unroll
            for (int mf = 0; mf < 2; ++mf) {
                const int mloc = m0 + wm * 32 + mf * 16 + col;
                const size_t idx = ((size_t)b * 128 + o) * M + mloc;
                Y[idx] = acc[of][mf][r] + Z[idx];
            }
        }
    }
}

struct QKVArgs {
    const u32* W0; const u32* W1; const u32* W2;
    const ush* X0; const ush* X1; const ush* X2;
};

// fused: qkv projections (blocks 0..1151) + bf16 transpose(s) (blocks 1152..)
__global__ __launch_bounds__(256) void qkv_tr_kernel(QKVArgs A,
        ush* __restrict__ vfm, ush* __restrict__ qktb,
        const ush* __restrict__ ts0, ush* __restrict__ td0,
        const ush* __restrict__ ts1, ush* __restrict__ td1)
{
    __shared__ __align__(16) ush Wh[64][64];
    __shared__ __align__(16) ush Xh[64][64];
    __shared__ ush ttile[32][34];
    const int bx = blockIdx.x;
    if (bx < 1152) {
        const int z = bx / 576, rem = bx % 576;
        const int y = rem / 96, x = rem % 96;
        const int wi = y >> 1;
        const u32* W = wi == 0 ? A.W0 : (wi == 1 ? A.W1 : A.W2);
        const ush* X = wi == 0 ? A.X0 : (wi == 1 ? A.X1 : A.X2);
        gemm_tile<0, 4, true>(W, 128, X, 128, nullptr, nullptr, vfm, qktb,
                        z, x * 64, (y & 1) * 64, y * 64, 384,
                        Wh, Xh);
    } else {
        int i = bx - 1152;
        const int which = i / 1536; i %= 1536;
        const ush* src = which ? ts1 : ts0;
        ush* dst = which ? td1 : td0;
        const int x = i & 63, y = (i >> 6) & 3, z = i >> 8;
        const int b = z / 3, t = z % 3;
        const int n0 = x * 32, c0 = y * 32;
        const int tx = threadIdx.x & 31, ty = threadIdx.x >> 5;
        #pragma unroll
        for (int p = 0; p < 4; ++p) {
            int c = c0 + ty + p * 8;
            ttile[ty + p * 8][tx] = src[((size_t)(b * C_ + c) * 3 + t) * N_ + n0 + tx];
        }
        __syncthreads();
        #pragma unroll
        for (int p = 0; p < 4; ++p) {
            int n = n0 + ty + p * 8;
            dst[((size_t)(b * N_ + n) * 3 + t) * C_ + c0 + tx] = ttile[tx][ty + p * 8];
        }
    }
}

// ---------------------------------------------------------------------------
// barrier-free split-K flash attention, XCD-chunked 1D grid (1024 blocks).
// ---------------------------------------------------------------------------
__global__ __launch_bounds__(256) void attn_mfma_kernel(
    const ush* __restrict__ vfm, const ush* __restrict__ qktb,
    ush* __restrict__ pacc, float* __restrict__ pml)
{
    __shared__ __align__(16) ush Pl[4][2][16][64];   // 16 KB

    const int flat = blockIdx.x;
    const int xcd  = flat & 7;
    const int slot = flat >> 3;          // 0..127
    const int bh   = xcd * 2 + (slot >> 6);   // 0..15
    const int q32  = slot & 63;

    const int tid = threadIdx.x;
    const int lane = tid & 63, wv = tid >> 6;
    const int col = lane & 15, grp = lane >> 4;
    const int c7  = col & 7;
    const int kz  = wv;
    const int ks0 = kz * (N_ / KSPLIT);

    const ush* Qpl = qktb + (size_t)bh * 131072;
    const ush* Kpl = qktb + (size_t)(16 + bh) * 131072;
    const ush* Vpl = vfm  + (size_t)bh * 98304;

    short8v qf[2][2];
    #pragma unroll
    for (int qi = 0; qi < 2; ++qi) {
        const int qg = q32 * 2 + qi;
        qf[qi][0] = *(const short8v*)(Qpl + ((size_t)qg * 2 + 0) * 512 + lane * 8);
        qf[qi][1] = *(const short8v*)(Qpl + ((size_t)qg * 2 + 1) * 512 + lane * 8);
    }

    f32x4 acc[2][3];
    #pragma unroll
    for (int qi = 0; qi < 2; ++qi)
        #pragma unroll
        for (int db = 0; db < 3; ++db) { f32x4 z = {0.f,0.f,0.f,0.f}; acc[qi][db] = z; }
    float m_i[2] = {0.f, 0.f};
    float l_l[2] = {0.f, 0.f};

    const int NT = (N_ / KSPLIT) / 64;   // 8 tiles of 64 keys
    for (int mt = 0; mt < NT; ++mt) {
        const int m0 = ks0 + mt * 64;

        short8v ka[4][2];
        #pragma unroll
        for (int kb = 0; kb < 4; ++kb) {
            const size_t kg = (m0 >> 4) + kb;
            ka[kb][0] = *(const short8v*)(Kpl + (kg * 2 + 0) * 512 + lane * 8);
            ka[kb][1] = *(const short8v*)(Kpl + (kg * 2 + 1) * 512 + lane * 8);
        }
        const int kt = m0 >> 6;
        short8v vf[2][3];
        #pragma unroll
        for (int hh = 0; hh < 2; ++hh)
            #pragma unroll
            for (int db = 0; db < 3; ++db)
                vf[hh][db] = *(const short8v*)(Vpl + (size_t)((kt * 2 + hh) * 3 + db) * 512 + lane * 8);

        f32x4 sf[2][4];
        __builtin_amdgcn_s_setprio(1);
        #pragma unroll
        for (int qi = 0; qi < 2; ++qi)
            #pragma unroll
            for (int kb = 0; kb < 4; ++kb) {
                f32x4 z = {0.f, 0.f, 0.f, 0.f};
                z = __builtin_amdgcn_mfma_f32_16x16x32_bf16(ka[kb][0], qf[qi][0], z, 0, 0, 0);
                z = __builtin_amdgcn_mfma_f32_16x16x32_bf16(ka[kb][1], qf[qi][1], z, 0, 0, 0);
                sf[qi][kb] = z;
            }
        __builtin_amdgcn_s_setprio(0);

        #pragma unroll
        for (int qi = 0; qi < 2; ++qi) {
            float psum = 0.f;
            #pragma unroll
            for (int kb = 0; kb < 4; ++kb) {
                float e0 = __expf(sf[qi][kb][0] - m_i[qi]);
                float e1 = __expf(sf[qi][kb][1] - m_i[qi]);
                float e2 = __expf(sf[qi][kb][2] - m_i[qi]);
                float e3 = __expf(sf[qi][kb][3] - m_i[qi]);
                psum += (e0 + e1) + (e2 + e3);
                u32 r0, r1;
                asm("v_cvt_pk_bf16_f32 %0, %1, %2" : "=v"(r0) : "v"(e0), "v"(e1));
                asm("v_cvt_pk_bf16_f32 %0, %1, %2" : "=v"(r1) : "v"(e2), "v"(e3));
                const int un = (4 * kb + grp) ^ (c7 << 1);
                uint2 pk2; pk2.x = r0; pk2.y = r1;
                *(uint2*)&Pl[wv][qi][col][un << 2] = pk2;
            }
            l_l[qi] += psum;
        }

        __builtin_amdgcn_s_setprio(1);
        #pragma unroll
        for (int qi = 0; qi < 2; ++qi)
            #pragma unroll
            for (int hh = 0; hh < 2; ++hh) {
                const int ur = (8 * hh + 2 * grp) ^ (c7 << 1);
                short8v pf = *(const short8v*)&Pl[wv][qi][col][ur << 2];
                #pragma unroll
                for (int db = 0; db < 3; ++db)
                    acc[qi][db] = __builtin_amdgcn_mfma_f32_16x16x32_bf16(vf[hh][db], pf, acc[qi][db], 0, 0, 0);
            }
        __builtin_amdgcn_s_setprio(0);

        #pragma unroll
        for (int qi = 0; qi < 2; ++qi) {
            float pmax = -1e30f;
            #pragma unroll
            for (int kb = 0; kb < 4; ++kb)
                #pragma unroll
                for (int r = 0; r < 4; ++r) pmax = fmaxf(pmax, sf[qi][kb][r]);
            pmax = fmaxf(pmax, __shfl_xor(pmax, 16, 64));
            pmax = fmaxf(pmax, __shfl_xor(pmax, 32, 64));
            if (!__all(pmax - m_i[qi] <= 8.0f)) {
                float mnew = fmaxf(m_i[qi], pmax);
                float sc = __expf(m_i[qi] - mnew);
                l_l[qi] *= sc;
                #pragma unroll
                for (int db = 0; db < 3; ++db) {
                    acc[qi][db][0] *= sc; acc[qi][db][1] *= sc;
                    acc[qi][db][2] *= sc; acc[qi][db][3] *= sc;
                }
                m_i[qi] = mnew;
            }
        }
    }

    const int ntile = q32 >> 1, qh = q32 & 1;
    const size_t pb = (size_t)(kz * 16 + bh) * 32 + ntile;
    #pragma unroll
    for (int qi = 0; qi < 2; ++qi) {
        float l = l_l[qi];
        l += __shfl_xor(l, 16, 64);
        l += __shfl_xor(l, 32, 64);
        const int q = qh * 32 + qi * 16 + col;
        #pragma unroll
        for (int db = 0; db < 3; ++db)
            #pragma unroll
            for (int r = 0; r < 4; ++r) {
                int d = db * 16 + grp * 4 + r;
                pacc[pb * 3072 + d * 64 + q] = f2bf(acc[qi][db][r]);
            }
        if (grp == 0) {
            pml[pb * 128 + q]      = m_i[qi];
            pml[pb * 128 + 64 + q] = l;
        }
    }
}

// ---------------------------------------------------------------------------
// fused: split-K reduce (blocks 0..511) + graph attention (blocks 512..4607)
// ---------------------------------------------------------------------------
__global__ __launch_bounds__(256) void reduce_graph_kernel(
    const ush* __restrict__ pacc, const float* __restrict__ pml,
    ush* __restrict__ ao,
    const ush* __restrict__ tq, const ush* __restrict__ tv,
    const int* __restrict__ idx, ush* __restrict__ gbuf)
{
    __shared__ float centerf[384];
    __shared__ ush nbr_l[16][384];
    __shared__ float sd[16];
    __shared__ int nbr_i[16];
    const int tid = threadIdx.x;

    if (blockIdx.x < 512) {
        // ============ split-K reduce ============
        const int nt = blockIdx.x & 31, bh = blockIdx.x >> 5;
        const int b = bh >> 3, h = bh & 7;
        const int q = tid & 63, dg = tid >> 6;

        size_t pb[KSPLIT];
        float m[KSPLIT], l[KSPLIT];
        #pragma unroll
        for (int kz = 0; kz < KSPLIT; ++kz) {
            pb[kz] = (size_t)(kz * 16 + bh) * 32 + nt;
            m[kz] = pml[pb[kz] * 128 + q];
            l[kz] = pml[pb[kz] * 128 + 64 + q];
        }
        float ms = -1e30f;
        #pragma unroll
        for (int kz = 0; kz < KSPLIT; ++kz) ms = fmaxf(ms, m[kz]);
        float w[KSPLIT], ls = 0.f;
        #pragma unroll
        for (int kz = 0; kz < KSPLIT; ++kz) { w[kz] = __expf(m[kz] - ms); ls += l[kz] * w[kz]; }
        const float inv = 1.f / ls;

        const size_t hb = ((size_t)(b * C_ + h * 16)) * 3 * N_;
        #pragma unroll
        for (int j = 0; j < 12; ++j) {
            int d = dg * 12 + j;
            float o = 0.f;
            #pragma unroll
            for (int kz = 0; kz < KSPLIT; ++kz)
                o += bf2f(pacc[pb[kz] * 3072 + d * 64 + q]) * w[kz];
            ao[hb + (size_t)d * N_ + nt * 64 + q] = f2bf(o * inv);
        }
    } else {
        // ============ graph attention ============
        const int j = blockIdx.x - 512;
        const int b = j >> 11, n = j & 2047;
        const ush* qrow = tq + (size_t)(b * N_ + n) * 384;
        for (int e = tid; e < 384; e += 256) centerf[e] = bf2f(qrow[e]);
        if (tid < 16) nbr_i[tid] = idx[(size_t)(b * N_ + n) * 16 + tid];
        __syncthreads();

        const int lane = tid & 63, wv = tid >> 6;
        for (int kk = 0; kk < 4; ++kk) {
            int k = wv * 4 + kk;
            const u32* vrow = (const u32*)(tv + ((size_t)b * N_ + nbr_i[k]) * 384);
            float p = 0.f;
            #pragma unroll
            for (int jj = 0; jj < 3; ++jj) {
                int e2 = lane + jj * 64;
                u32 v2 = vrow[e2];
                ((u32*)nbr_l[k])[e2] = v2;
                p += centerf[e2 * 2]     * bf2f((ush)(v2 & 0xffff))
                   + centerf[e2 * 2 + 1] * bf2f((ush)(v2 >> 16));
            }
            #pragma unroll
            for (int off = 32; off; off >>= 1) p += __shfl_down(p, off, 64);
            if (lane == 0) sd[k] = p * 0.05103103630798288f;
        }
        __syncthreads();

        float mx = -1e30f;
        #pragma unroll
        for (int k = 0; k < 16; ++k) mx = fmaxf(mx, sd[k]);
        float a[16]; float ssum = 0.f;
        #pragma unroll
        for (int k = 0; k < 16; ++k) { a[k] = __expf(sd[k] - mx); ssum += a[k]; }
        float inv = 1.f / ssum;

        for (int e = tid; e < 384; e += 256) {
            float accv = 0.f;
            #pragma unroll
            for (int k = 0; k < 16; ++k)
                accv += a[k] * bf2f(nbr_l[k][e]);
            accv *= inv;
            float ce = centerf[e];
            int t = e >> 7, c = e & 127;
            size_t gb = ((size_t)(b * N_ + n) * 3 + t) * 256;
            gbuf[gb + c]       = f2bf(accv - ce);
            gbuf[gb + 128 + c] = f2bf(ce);
        }
    }
}

// ---------------------------------------------------------------------------
// vn_leaky: reads h1hd combined buffer (x = rows 0..511, d = rows 512..1023)
// ---------------------------------------------------------------------------
__global__ __launch_bounds__(256) void leaky_kernel(const ush* __restrict__ h1hd,
                                                    ush* __restrict__ y)
{
    size_t p = (size_t)blockIdx.x * 256 + threadIdx.x;
    size_t bh = p / N_, n = p % N_;
    size_t b = bh / HID_, hid = bh % HID_;
    size_t xb = ((size_t)(b * 1024 + hid)) * 3 * N_ + n;
    size_t db = ((size_t)(b * 1024 + 512 + hid)) * 3 * N_ + n;
    float x0 = bf2f(h1hd[xb]), x1 = bf2f(h1hd[xb + N_]), x2 = bf2f(h1hd[xb + 2 * N_]);
    float d0 = bf2f(h1hd[db]), d1 = bf2f(h1hd[db + N_]), d2 = bf2f(h1hd[db + 2 * N_]);
    float dot = x0 * d0 + x1 * d1 + x2 * d2;
    float dsq = d0 * d0 + d1 * d1 + d2 * d2;
    float f = dot / (dsq + EPS_);
    bool pos = dot >= 0.f;
    float y0 = pos ? x0 : x0 - f * d0;
    float y1 = pos ? x1 : x1 - f * d1;
    float y2 = pos ? x2 : x2 - f * d2;
    size_t base = bh * 3 * N_ + n;
    y[base]          = f2bf(NS_ * x0 + (1.f - NS_) * y0);
    y[base + N_]     = f2bf(NS_ * x1 + (1.f - NS_) * y1);
    y[base + 2 * N_] = f2bf(NS_ * x2 + (1.f - NS_) * y2);
}

// ---------------------------------------------------------------------------
extern "C" void kernel_launch(void* const* d_in, const int* in_sizes, int n_in,
                              void* d_out, int out_size, void* d_ws, size_t ws_size,
                              hipStream_t stream)
{
    const float* q_in = (const float*)d_in[0];
    const float* v_in = (const float*)d_in[1];
    const int*   idx_s = (const int*)d_in[4];
    const int*   idx_c = (const int*)d_in[5];
    const float* g1 = (const float*)d_in[6];
    const float* b1 = (const float*)d_in[7];
    const float* g2 = (const float*)d_in[8];
    const float* b2 = (const float*)d_in[9];
    const float* gq = (const float*)d_in[10];
    const float* bq = (const float*)d_in[11];
    const float* gv = (const float*)d_in[12];
    const float* bv = (const float*)d_in[13];
    float* out = (float*)d_out;
    float* ws  = (float*)d_ws;

    const size_t S1 = (size_t)B_ * C_ * 3 * N_; // 1572864 elems
    ush*   gbuf_b= (ush*)(ws);         // 0 (6.3MB; live reduce_graph -> wm2)
    float* dtmp  = (float*)(ws);       // 0: 1MB dfuse partials (dead before phase A graph)
    ush*   nx_b  = (ush*)(ws + 2*S1);  // 2 (half)
    ush*   nv_b  = (ush*)(ws + 3*S1);  // 3 (half)
    ush*   vfm   = (ush*)(ws + 4*S1);  // 4: 3MB
    ush*   qktb  = (ush*)(ws + 5*S1) + S1;  // 5.5-6.84: 8.4MB
    ush*   ao_b  = (ush*)(ws + 7*S1);  // 7 (half)
    float* qa    = ws + 12*S1;         // 12
    float* qb    = ws + 13*S1;         // 13
    ush*   t1_b  = (ush*)(ws + 14*S1); // 14 (half)
    ush*   t2_b  = (ush*)(ws + 15*S1); // 15 (half)
    u32*   wsp   = (u32*)(ws + 16*S1); // 16+
    // split-K attention partials (attn->reduce window only; KSPLIT=4: 12.6MB)
    ush*   pacc  = (ush*)(ws + 8*S1);  // 8-9
    float* pml   = (float*)(ws + 2*S1);// 2 (attn after qkv consumed nx_b)
    // phase C aliases (all bf16):
    ush*   h1hd  = (ush*)(ws + 8*S1);  // 8-11: (B,1024,M) bf16 = 25.2MB (pacc dead)
    ush*   h1_b2 = (ush*)(ws + 14*S1); // 14-15 (t1/t2 dead): (B,512,M) bf16

    // weight planes: 8 split-converted + Dfused + 4 fused Wfa/Wfb
    const int wn[8]   = {16384,16384,16384, 16384,16384,16384, 65536,65536};
    const int wsrc[8] = {14,15,16, 20,21,22, 26,28};
    u32* wd[8];
    {
        int off = 0;
        for (int i = 0; i < 8; ++i) { wd[i] = wsp + off; off += wn[i]; }
    }
    u32 *Wq_s = wd[0], *Wk_s = wd[1], *Wv_s = wd[2];
    u32 *Wq_c = wd[3], *Wk_c = wd[4], *Wv_c = wd[5];
    u32 *W1D  = wd[6];                 // 1024x128: rows 0-511 = W1, 512-1023 = Dfused
    u32 *Dfused = wsp + 98304 + 65536; // rows 512-1023 of W1D
    u32 *W2   = wsp + 229376;
    u32* Wfa_s = wsp + 491520;
    u32* Wfb_s = Wfa_s + 16384;
    u32* Wfa_c = Wfb_s + 32768;
    u32* Wfb_c = Wfa_c + 16384;

    {
        SetupArgs a{};
        for (int i = 0; i < 8; ++i) {
            a.src[i] = (const float*)d_in[wsrc[i]];
            a.n[i]   = wn[i];
            a.scale[i] = 1.f;
        }
        a.dst[0] = Wq_s; a.dst[1] = Wk_s; a.dst[2] = Wv_s;
        a.dst[3] = Wq_c; a.dst[4] = Wk_c; a.dst[5] = Wv_c;
        a.dst[6] = W1D;  a.dst[7] = W2;
        a.scale[0] = 0.14433756729740643f;  // Wq_s: fold 1/sqrt(48)
        a.scale[3] = 0.14433756729740643f;  // Wq_c
        a.Wm[0] = (const float*)d_in[19]; a.Wo[0] = (const float*)d_in[17]; a.We[0] = (const float*)d_in[18];
        a.Wm[1] = (const float*)d_in[25]; a.Wo[1] = (const float*)d_in[23]; a.We[1] = (const float*)d_in[24];
        a.Wfa[0] = Wfa_s; a.Wfb[0] = Wfb_s;
        a.Wfa[1] = Wfa_c; a.Wfb[1] = Wfb_c;
        a.qkz = (uint4*)qktb;
        setup_kernel<<<dim3(8192 + 384 + 1024), 256, 0, stream>>>(a);
    }
    dfuse_part_kernel<<<dim3(1024), 256, 0, stream>>>((const float*)d_in[27],
                                                      (const float*)d_in[26], dtmp);
    dfuse_comb_kernel<<<dim3(256), 256, 0, stream>>>(dtmp, Dfused);

    dim3 gwm(96, 2, B_);

    // ---- Phase A: self attention block ----
    {
        LNArgs la{};
        la.x[0] = q_in; la.g[0] = g1; la.bt[0] = b1; la.ysp[0] = nx_b;
        ln_kernel<<<dim3(64, B_, 1), 256, 0, stream>>>(la);
    }
    {
        QKVArgs A{Wq_s, Wk_s, Wv_s, nx_b, nx_b, nx_b};
        qkv_tr_kernel<<<dim3(1152 + 1536), 256, 0, stream>>>(A, vfm, qktb, nx_b, t1_b, nullptr, nullptr);
    }
    attn_mfma_kernel<<<dim3(1024), 256, 0, stream>>>(vfm, qktb, pacc, pml);
    reduce_graph_kernel<<<dim3(512 + 4096), 256, 0, stream>>>(pacc, pml, ao_b, t1_b, t1_b, idx_s, gbuf_b);
    wm2_kernel<<<gwm, 256, 0, stream>>>(Wfa_s, Wfb_s, ao_b, gbuf_b, q_in, qa);

    // ---- Phase B: cross attention block ----
    {
        LNArgs la{};
        la.x[0] = qa;   la.g[0] = gq; la.bt[0] = bq; la.ysp[0] = nx_b;
        la.x[1] = v_in; la.g[1] = gv; la.bt[1] = bv; la.ysp[1] = nv_b;
        ln_kernel<<<dim3(64, B_, 2), 256, 0, stream>>>(la);
    }
    {
        QKVArgs A{Wq_c, Wk_c, Wv_c, nx_b, nv_b, nv_b};
        qkv_tr_kernel<<<dim3(1152 + 3072), 256, 0, stream>>>(A, vfm, qktb, nx_b, t1_b, nv_b, t2_b);
    }
    attn_mfma_kernel<<<dim3(1024), 256, 0, stream>>>(vfm, qktb, pacc, pml);
    reduce_graph_kernel<<<dim3(512 + 4096), 256, 0, stream>>>(pacc, pml, ao_b, t1_b, t2_b, idx_c, gbuf_b);
    wm2_kernel<<<gwm, 256, 0, stream>>>(Wfa_c, Wfb_c, ao_b, gbuf_b, qa, qb);

    // ---- Phase C: vector MLP (fused W1+Dfused single GEMM, K=128) ----
    {
        LNArgs la{};
        la.x[0] = qb; la.g[0] = g2; la.bt[0] = b2; la.ysp[0] = nx_b;
        ln_kernel<<<dim3(64, B_, 1), 256, 0, stream>>>(la);
    }
    gemm_kernel2<0,3,true><<<dim3(96, 16, B_), 256, 0, stream>>>(W1D, 128, nx_b, nullptr, nullptr, h1hd, 1024, 0, 128);
    leaky_kernel<<<dim3((B_ * HID_ * N_) / 256), 256, 0, stream>>>(h1hd, h1_b2);
    gemm_kernel2<0,0,true><<<dim3(96, 2, B_), 256, 0, stream>>>(W2, 512, h1_b2, qb, out, nullptr, 128, 0, 512);
}

// Round 24
// 219.813 us; speedup vs baseline: 1.5905x; 1.0695x over previous
//
#include <hip/hip_runtime.h>
#include <math.h>

#define B_    2
#define C_    128
#define N_    2048
#define HID_  512
#define HEADS_ 8
#define EPS_  1e-6f
#define NS_   0.2f
#define KSPLIT 4

typedef __attribute__((ext_vector_type(8))) short short8v;  // 8 bf16
typedef __attribute__((ext_vector_type(4))) float f32x4;
typedef unsigned short ush;
typedef unsigned int u32;

__device__ inline ush f2bf(float f) {
    unsigned u = __float_as_uint(f);
    u += 0x7FFF + ((u >> 16) & 1);          // round-to-nearest-even
    return (ush)(u >> 16);
}
__device__ inline float bf2f(ush u) { return __uint_as_float((u32)u << 16); }

// pack float -> (hi bf16 << 16) | lo bf16
__device__ inline u32 splitpack(float x) {
    ush hi = f2bf(x);
    float hf = __uint_as_float((u32)hi << 16);
    ush lo = f2bf(x - hf);
    return ((u32)hi << 16) | (u32)lo;
}

__device__ inline void unpack_hi(const u32* buf, short8v& h0, short8v& h1) {
    ush h[16];
    #pragma unroll
    for (int j = 0; j < 16; ++j) h[j] = (ush)(buf[j] >> 16);
    h0 = *(short8v*)&h[0]; h1 = *(short8v*)&h[8];
}

// ---------------------------------------------------------------------------
// vec_layernorm, z-indexed multi-input, single global read pass (registers)
// ---------------------------------------------------------------------------
struct LNArgs {
    const float* x[2]; const float* g[2]; const float* bt[2]; ush* ysp[2];
};
__global__ __launch_bounds__(256) void ln_kernel(LNArgs a)
{
    __shared__ float red1[8][32];
    __shared__ float red2[8][32];
    const int s = blockIdx.z;
    const float* x = a.x[s];
    const float* gma = a.g[s];
    const float* bta = a.bt[s];
    ush* ysp = a.ysp[s];

    const int b  = blockIdx.y;
    const int n0 = blockIdx.x * 32;
    const int nn = threadIdx.x & 31;
    const int cg = threadIdx.x >> 5;

    float xr0[16], xr1[16], xr2[16], nrr[16];
    float s1 = 0.f, s2 = 0.f;
    #pragma unroll
    for (int it = 0; it < 16; ++it) {
        int c = it * 8 + cg;
        size_t base = ((size_t)(b * C_ + c) * 3) * N_ + n0 + nn;
        float x0 = x[base], x1 = x[base + N_], x2 = x[base + 2 * N_];
        float nr = sqrtf(x0 * x0 + x1 * x1 + x2 * x2 + EPS_);
        xr0[it] = x0; xr1[it] = x1; xr2[it] = x2; nrr[it] = nr;
        s1 += nr; s2 += nr * nr;
    }
    red1[cg][nn] = s1; red2[cg][nn] = s2;
    __syncthreads();
    float S1 = 0.f, S2 = 0.f;
    #pragma unroll
    for (int g = 0; g < 8; ++g) { S1 += red1[g][nn]; S2 += red2[g][nn]; }
    float mu   = S1 * (1.f / 128.f);
    float var  = S2 * (1.f / 128.f) - mu * mu;
    float rstd = rsqrtf(var + EPS_);

    #pragma unroll
    for (int it = 0; it < 16; ++it) {
        int c = it * 8 + cg;
        float nr = nrr[it];
        float ln = (nr - mu) * rstd * gma[c] + bta[c];
        float sc = ln / (nr + EPS_);
        size_t base = ((size_t)(b * C_ + c) * 3) * N_ + n0 + nn;
        ysp[base]          = f2bf(xr0[it] * sc);
        ysp[base + N_]     = f2bf(xr1[it] * sc);
        ysp[base + 2 * N_] = f2bf(xr2[it] * sc);
    }
}

// ---------------------------------------------------------------------------
// fused setup: 9 weight split-conversions (blocks 0..9215) + output-mix
// weight products Wfa/Wfb (blocks 9216..9599) + qktb zeroing (9600..10623)
// ---------------------------------------------------------------------------
struct SetupArgs {
    const float* src[9]; u32* dst[9]; int n[9]; float scale[9];
    const float* Wm[2]; const float* Wo[2]; const float* We[2];
    u32* Wfa[2]; u32* Wfb[2];
    uint4* qkz;
};
__global__ __launch_bounds__(256) void setup_kernel(SetupArgs a)
{
    const int bx = blockIdx.x;
    if (bx < 9216) {
        const int w = bx / 1024;
        const int i = (bx % 1024) * 256 + threadIdx.x;
        if (i < a.n[w]) a.dst[w][i] = splitpack(a.src[w][i] * a.scale[w]);
    } else if (bx < 9600) {
        const int tg = (bx - 9216) * 256 + threadIdx.x;   // 0..98303
        const int p = tg / 49152;
        const int rem = tg % 49152;
        if (rem < 16384) {
            const int o = rem >> 7, k = rem & 127;
            const float* Wm = a.Wm[p];
            const float* Wo = a.Wo[p];
            float acc = 0.f;
            #pragma unroll 4
            for (int c = 0; c < 128; ++c)
                acc += Wm[o * 256 + c] * Wo[c * 128 + k];
            a.Wfa[p][o * 128 + k] = splitpack(acc);
        } else {
            const int r2 = rem - 16384;
            const int o = r2 >> 8, k = r2 & 255;
            const float* Wm = a.Wm[p];
            const float* We = a.We[p];
            float acc = 0.f;
            #pragma unroll 4
            for (int c = 0; c < 128; ++c)
                acc += Wm[o * 256 + 128 + c] * We[c * 256 + k];
            a.Wfb[p][o * 256 + k] = splitpack(acc);
        }
    } else {
        // zero qktb (524288 uint4 = 8.4MB); 1024 blocks x 512 uint4
        const size_t i0 = ((size_t)(bx - 9600) * 256 + threadIdx.x) * 2;
        uint4 z = {0, 0, 0, 0};
        a.qkz[i0]     = z;
        a.qkz[i0 + 1] = z;
    }
}

// ---------------------------------------------------------------------------
// bf16 MFMA GEMM core (hi-only). XBF: X input is bf16 ush (else split u32).
// XMODE 0: X[(b*K + c)*M + m]   XMODE 1: X[((b*N+n)*3+t)*K + c], m = t*N+n
// OMODE 0: fp32(+Z)  3: bf16 Ybf  4: qkv fragment-major
// ---------------------------------------------------------------------------
template <int XMODE, int OMODE, bool XBF>
__device__ __forceinline__ void gemm_tile(
    const u32* __restrict__ Wsp, int wstride,
    const void* __restrict__ Xv, int K,
    const float* __restrict__ Z, float* __restrict__ Y,
    ush* __restrict__ Ybf, ush* __restrict__ Ytr,
    int b, int m0, int o0loc, int oglob, int Ostr,
    ush (*Wh)[64], ush (*Xh)[64])
{
    const int M = 3 * N_;
    const int tid = threadIdx.x;
    const int lane = tid & 63, wv = tid >> 6;
    const int col = lane & 15, grp = lane >> 4;
    const int wo = wv >> 1, wm = wv & 1;

    f32x4 acc[2][2];
    #pragma unroll
    for (int i = 0; i < 2; ++i)
        #pragma unroll
        for (int j = 0; j < 2; ++j) { f32x4 z = {0.f,0.f,0.f,0.f}; acc[i][j] = z; }

    for (int kk = 0; kk < K; kk += 64) {
        {
            const int o = tid >> 2, kg = tid & 3;
            const u32* src = Wsp + (size_t)(o0loc + o) * wstride + kk + kg * 16;
            u32 buf[16];
            #pragma unroll
            for (int j = 0; j < 4; ++j) *(uint4*)&buf[j * 4] = *(const uint4*)(src + j * 4);
            const int s0 = ((kg * 2)     ^ (o & 7)) << 3;
            const int s1 = ((kg * 2 + 1) ^ (o & 7)) << 3;
            short8v h0, h1; unpack_hi(buf, h0, h1);
            *(short8v*)&Wh[o][s0] = h0; *(short8v*)&Wh[o][s1] = h1;
        }
        if (XMODE == 0) {
            const int m = lane, kq = wv;
            const int s0 = ((kq * 2)     ^ (m & 7)) << 3;
            const int s1 = ((kq * 2 + 1) ^ (m & 7)) << 3;
            if (XBF) {
                const ush* src = (const ush*)Xv + ((size_t)b * K + kk + kq * 16) * M + m0 + m;
                ush h[16];
                #pragma unroll
                for (int j = 0; j < 16; ++j) h[j] = src[(size_t)j * M];
                *(short8v*)&Xh[m][s0] = *(short8v*)&h[0];
                *(short8v*)&Xh[m][s1] = *(short8v*)&h[8];
            } else {
                const u32* src = (const u32*)Xv + ((size_t)b * K + kk + kq * 16) * M + m0 + m;
                u32 buf[16];
                #pragma unroll
                for (int j = 0; j < 16; ++j) buf[j] = src[(size_t)j * M];
                short8v h0, h1; unpack_hi(buf, h0, h1);
                *(short8v*)&Xh[m][s0] = h0; *(short8v*)&Xh[m][s1] = h1;
            }
        } else {
            const int m = tid >> 2, kg = tid & 3;
            const int mg = m0 + m;
            const int n = mg & (N_ - 1), t = mg >> 11;
            const int s0 = ((kg * 2)     ^ (m & 7)) << 3;
            const int s1 = ((kg * 2 + 1) ^ (m & 7)) << 3;
            const ush* src = (const ush*)Xv + ((size_t)(b * N_ + n) * 3 + t) * K + kk + kg * 16;
            ush h[16];
            *(uint4*)&h[0] = *(const uint4*)(src);
            *(uint4*)&h[8] = *(const uint4*)(src + 8);
            *(short8v*)&Xh[m][s0] = *(short8v*)&h[0];
            *(short8v*)&Xh[m][s1] = *(short8v*)&h[8];
        }
        __syncthreads();
        #pragma unroll
        for (int kc = 0; kc < 2; ++kc) {
            const int sk = ((kc * 4 + grp) ^ (col & 7)) << 3;
            short8v ah0 = *(const short8v*)&Wh[wo * 32 + col][sk];
            short8v ah1 = *(const short8v*)&Wh[wo * 32 + 16 + col][sk];
            short8v xh0 = *(const short8v*)&Xh[wm * 32 + col][sk];
            short8v xh1 = *(const short8v*)&Xh[wm * 32 + 16 + col][sk];
            acc[0][0] = __builtin_amdgcn_mfma_f32_16x16x32_bf16(ah0, xh0, acc[0][0], 0, 0, 0);
            acc[0][1] = __builtin_amdgcn_mfma_f32_16x16x32_bf16(ah0, xh1, acc[0][1], 0, 0, 0);
            acc[1][0] = __builtin_amdgcn_mfma_f32_16x16x32_bf16(ah1, xh0, acc[1][0], 0, 0, 0);
            acc[1][1] = __builtin_amdgcn_mfma_f32_16x16x32_bf16(ah1, xh1, acc[1][1], 0, 0, 0);
        }
        __syncthreads();
    }
    #pragma unroll
    for (int of = 0; of < 2; ++of) {
        #pragma unroll
        for (int r = 0; r < 4; ++r) {
            const int o = oglob + wo * 32 + of * 16 + grp * 4 + r;
            #pragma unroll
            for (int mf = 0; mf < 2; ++mf) {
                const int mloc = m0 + wm * 32 + mf * 16 + col;
                const size_t idx = ((size_t)b * Ostr + o) * M + mloc;
                float v = acc[of][mf][r];
                if (OMODE == 0) {
                    if (Z) v += Z[idx];
                    Y[idx] = v;
                }
                if (OMODE == 3) Ybf[idx] = f2bf(v);
                if (OMODE == 4) {
                    ush bv = f2bf(v);
                    const int t = mloc >> 11, n = mloc & (N_ - 1);
                    const int h = (o >> 4) & 7, cl = o & 15;
                    const int d = cl * 3 + t;
                    if (o >= 256) {
                        const int kt = n >> 6, hh = (n >> 5) & 1, db = d >> 4;
                        const size_t idx2 = ((size_t)(b * 8 + h) * 192
                                           + (kt * 2 + hh) * 3 + db) * 512
                                          + (((n >> 3) & 3) * 16 + (d & 15)) * 8 + (n & 7);
                        Ybf[idx2] = bv;
                    } else {
                        const int isK = (o >> 7) & 1;
                        const int qg = n >> 4, half = d >> 5;
                        const size_t idx2 = ((size_t)(isK * 16 + b * 8 + h) * 256
                                           + qg * 2 + half) * 512
                                          + (((d >> 3) & 3) * 16 + (n & 15)) * 8 + (d & 7);
                        Ytr[idx2] = bv;
                    }
                }
            }
        }
    }
}

template <int XMODE, int OMODE, bool XBF>
__global__ __launch_bounds__(256) void gemm_kernel2(
    const u32* __restrict__ Wsp, int wstride,
    const void* __restrict__ Xv,
    const float* __restrict__ Z,
    float* __restrict__ Y, ush* __restrict__ Ybf,
    int Ostr, int obase, int K)
{
    __shared__ __align__(16) ush Wh[64][64];
    __shared__ __align__(16) ush Xh[64][64];
    gemm_tile<XMODE, OMODE, XBF>(Wsp, wstride, Xv, K, Z, Y, Ybf, nullptr,
                            blockIdx.z, blockIdx.x * 64,
                            blockIdx.y * 64, obase + blockIdx.y * 64, Ostr,
                            Wh, Xh);
}

// ---------------------------------------------------------------------------
// fused output mix: Y = Wfa*ao (K=128, XMODE0) + Wfb*gbuf (K=256, XMODE1) + Z
// ---------------------------------------------------------------------------
__global__ __launch_bounds__(256) void wm2_kernel(
    const u32* __restrict__ Wfa, const u32* __restrict__ Wfb,
    const ush* __restrict__ ao, const ush* __restrict__ gb,
    const float* __restrict__ Z, float* __restrict__ Y)
{
    __shared__ __align__(16) ush Wh[64][64];
    __shared__ __align__(16) ush Xh[64][64];
    const int M = 3 * N_;
    const int b = blockIdx.z;
    const int m0 = blockIdx.x * 64;
    const int o0 = blockIdx.y * 64;
    const int tid = threadIdx.x;
    const int lane = tid & 63, wv = tid >> 6;
    const int col = lane & 15, grp = lane >> 4;
    const int wo = wv >> 1, wm = wv & 1;

    f32x4 acc[2][2];
    #pragma unroll
    for (int i = 0; i < 2; ++i)
        #pragma unroll
        for (int j = 0; j < 2; ++j) { f32x4 z = {0.f,0.f,0.f,0.f}; acc[i][j] = z; }

    for (int kk = 0; kk < 128; kk += 64) {
        {
            const int o = tid >> 2, kg = tid & 3;
            const u32* src = Wfa + (size_t)(o0 + o) * 128 + kk + kg * 16;
            u32 buf[16];
            #pragma unroll
            for (int j = 0; j < 4; ++j) *(uint4*)&buf[j * 4] = *(const uint4*)(src + j * 4);
            const int s0 = ((kg * 2)     ^ (o & 7)) << 3;
            const int s1 = ((kg * 2 + 1) ^ (o & 7)) << 3;
            short8v h0, h1; unpack_hi(buf, h0, h1);
            *(short8v*)&Wh[o][s0] = h0; *(short8v*)&Wh[o][s1] = h1;
        }
        {
            const int m = lane, kq = wv;
            const int s0 = ((kq * 2)     ^ (m & 7)) << 3;
            const int s1 = ((kq * 2 + 1) ^ (m & 7)) << 3;
            const ush* src = ao + ((size_t)b * 128 + kk + kq * 16) * M + m0 + m;
            ush h[16];
            #pragma unroll
            for (int j = 0; j < 16; ++j) h[j] = src[(size_t)j * M];
            *(short8v*)&Xh[m][s0] = *(short8v*)&h[0];
            *(short8v*)&Xh[m][s1] = *(short8v*)&h[8];
        }
        __syncthreads();
        #pragma unroll
        for (int kc = 0; kc < 2; ++kc) {
            const int sk = ((kc * 4 + grp) ^ (col & 7)) << 3;
            short8v ah0 = *(const short8v*)&Wh[wo * 32 + col][sk];
            short8v ah1 = *(const short8v*)&Wh[wo * 32 + 16 + col][sk];
            short8v xh0 = *(const short8v*)&Xh[wm * 32 + col][sk];
            short8v xh1 = *(const short8v*)&Xh[wm * 32 + 16 + col][sk];
            acc[0][0] = __builtin_amdgcn_mfma_f32_16x16x32_bf16(ah0, xh0, acc[0][0], 0, 0, 0);
            acc[0][1] = __builtin_amdgcn_mfma_f32_16x16x32_bf16(ah0, xh1, acc[0][1], 0, 0, 0);
            acc[1][0] = __builtin_amdgcn_mfma_f32_16x16x32_bf16(ah1, xh0, acc[1][0], 0, 0, 0);
            acc[1][1] = __builtin_amdgcn_mfma_f32_16x16x32_bf16(ah1, xh1, acc[1][1], 0, 0, 0);
        }
        __syncthreads();
    }

    for (int kk = 0; kk < 256; kk += 64) {
        {
            const int o = tid >> 2, kg = tid & 3;
            const u32* src = Wfb + (size_t)(o0 + o) * 256 + kk + kg * 16;
            u32 buf[16];
            #pragma unroll
            for (int j = 0; j < 4; ++j) *(uint4*)&buf[j * 4] = *(const uint4*)(src + j * 4);
            const int s0 = ((kg * 2)     ^ (o & 7)) << 3;
            const int s1 = ((kg * 2 + 1) ^ (o & 7)) << 3;
            short8v h0, h1; unpack_hi(buf, h0, h1);
            *(short8v*)&Wh[o][s0] = h0; *(short8v*)&Wh[o][s1] = h1;
        }
        {
            const int m = tid >> 2, kg = tid & 3;
            const int mg = m0 + m;
            const int n = mg & (N_ - 1), t = mg >> 11;
            const int s0 = ((kg * 2)     ^ (m & 7)) << 3;
            const int s1 = ((kg * 2 + 1) ^ (m & 7)) << 3;
            const ush* src = gb + ((size_t)(b * N_ + n) * 3 + t) * 256 + kk + kg * 16;
            ush h[16];
            *(uint4*)&h[0] = *(const uint4*)(src);
            *(uint4*)&h[8] = *(const uint4*)(src + 8);
            *(short8v*)&Xh[m][s0] = *(short8v*)&h[0];
            *(short8v*)&Xh[m][s1] = *(short8v*)&h[8];
        }
        __syncthreads();
        #pragma unroll
        for (int kc = 0; kc < 2; ++kc) {
            const int sk = ((kc * 4 + grp) ^ (col & 7)) << 3;
            short8v ah0 = *(const short8v*)&Wh[wo * 32 + col][sk];
            short8v ah1 = *(const short8v*)&Wh[wo * 32 + 16 + col][sk];
            short8v xh0 = *(const short8v*)&Xh[wm * 32 + col][sk];
            short8v xh1 = *(const short8v*)&Xh[wm * 32 + 16 + col][sk];
            acc[0][0] = __builtin_amdgcn_mfma_f32_16x16x32_bf16(ah0, xh0, acc[0][0], 0, 0, 0);
            acc[0][1] = __builtin_amdgcn_mfma_f32_16x16x32_bf16(ah0, xh1, acc[0][1], 0, 0, 0);
            acc[1][0] = __builtin_amdgcn_mfma_f32_16x16x32_bf16(ah1, xh0, acc[1][0], 0, 0, 0);
            acc[1][1] = __builtin_amdgcn_mfma_f32_16x16x32_bf16(ah1, xh1, acc[1][1], 0, 0, 0);
        }
        __syncthreads();
    }

    #pragma unroll
    for (int of = 0; of < 2; ++of) {
        #pragma unroll
        for (int r = 0; r < 4; ++r) {
            const int o = o0 + wo * 32 + of * 16 + grp * 4 + r;
            #pragma unroll
            for (int mf = 0; mf < 2; ++mf) {
                const int mloc = m0 + wm * 32 + mf * 16 + col;
                const size_t idx = ((size_t)b * 128 + o) * M + mloc;
                Y[idx] = acc[of][mf][r] + Z[idx];
            }
        }
    }
}

struct QKVArgs {
    const u32* W0; const u32* W1; const u32* W2;
    const ush* X0; const ush* X1; const ush* X2;
};

// fused: qkv projections (blocks 0..1151) + bf16 transpose(s) (blocks 1152..)
__global__ __launch_bounds__(256) void qkv_tr_kernel(QKVArgs A,
        ush* __restrict__ vfm, ush* __restrict__ qktb,
        const ush* __restrict__ ts0, ush* __restrict__ td0,
        const ush* __restrict__ ts1, ush* __restrict__ td1)
{
    __shared__ __align__(16) ush Wh[64][64];
    __shared__ __align__(16) ush Xh[64][64];
    __shared__ ush ttile[32][34];
    const int bx = blockIdx.x;
    if (bx < 1152) {
        const int z = bx / 576, rem = bx % 576;
        const int y = rem / 96, x = rem % 96;
        const int wi = y >> 1;
        const u32* W = wi == 0 ? A.W0 : (wi == 1 ? A.W1 : A.W2);
        const ush* X = wi == 0 ? A.X0 : (wi == 1 ? A.X1 : A.X2);
        gemm_tile<0, 4, true>(W, 128, X, 128, nullptr, nullptr, vfm, qktb,
                        z, x * 64, (y & 1) * 64, y * 64, 384,
                        Wh, Xh);
    } else {
        int i = bx - 1152;
        const int which = i / 1536; i %= 1536;
        const ush* src = which ? ts1 : ts0;
        ush* dst = which ? td1 : td0;
        const int x = i & 63, y = (i >> 6) & 3, z = i >> 8;
        const int b = z / 3, t = z % 3;
        const int n0 = x * 32, c0 = y * 32;
        const int tx = threadIdx.x & 31, ty = threadIdx.x >> 5;
        #pragma unroll
        for (int p = 0; p < 4; ++p) {
            int c = c0 + ty + p * 8;
            ttile[ty + p * 8][tx] = src[((size_t)(b * C_ + c) * 3 + t) * N_ + n0 + tx];
        }
        __syncthreads();
        #pragma unroll
        for (int p = 0; p < 4; ++p) {
            int n = n0 + ty + p * 8;
            dst[((size_t)(b * N_ + n) * 3 + t) * C_ + c0 + tx] = ttile[tx][ty + p * 8];
        }
    }
}

// ---------------------------------------------------------------------------
// barrier-free split-K flash attention, XCD-chunked 1D grid (1024 blocks).
// KSPLIT=4: each wave owns kz = its wave index, 32 queries x 512 keys.
// ---------------------------------------------------------------------------
__global__ __launch_bounds__(256) void attn_mfma_kernel(
    const ush* __restrict__ vfm, const ush* __restrict__ qktb,
    ush* __restrict__ pacc, float* __restrict__ pml)
{
    __shared__ __align__(16) ush Pl[4][2][16][64];   // 16 KB

    const int flat = blockIdx.x;
    const int xcd  = flat & 7;
    const int slot = flat >> 3;          // 0..127
    const int bh   = xcd * 2 + (slot >> 6);   // 0..15
    const int q32  = slot & 63;

    const int tid = threadIdx.x;
    const int lane = tid & 63, wv = tid >> 6;
    const int col = lane & 15, grp = lane >> 4;
    const int c7  = col & 7;
    const int kz  = wv;
    const int ks0 = kz * (N_ / KSPLIT);

    const ush* Qpl = qktb + (size_t)bh * 131072;
    const ush* Kpl = qktb + (size_t)(16 + bh) * 131072;
    const ush* Vpl = vfm  + (size_t)bh * 98304;

    short8v qf[2][2];
    #pragma unroll
    for (int qi = 0; qi < 2; ++qi) {
        const int qg = q32 * 2 + qi;
        qf[qi][0] = *(const short8v*)(Qpl + ((size_t)qg * 2 + 0) * 512 + lane * 8);
        qf[qi][1] = *(const short8v*)(Qpl + ((size_t)qg * 2 + 1) * 512 + lane * 8);
    }

    f32x4 acc[2][3];
    #pragma unroll
    for (int qi = 0; qi < 2; ++qi)
        #pragma unroll
        for (int db = 0; db < 3; ++db) { f32x4 z = {0.f,0.f,0.f,0.f}; acc[qi][db] = z; }
    float m_i[2] = {0.f, 0.f};
    float l_l[2] = {0.f, 0.f};

    const int NT = (N_ / KSPLIT) / 64;   // 8 tiles of 64 keys
    for (int mt = 0; mt < NT; ++mt) {
        const int m0 = ks0 + mt * 64;

        short8v ka[4][2];
        #pragma unroll
        for (int kb = 0; kb < 4; ++kb) {
            const size_t kg = (m0 >> 4) + kb;
            ka[kb][0] = *(const short8v*)(Kpl + (kg * 2 + 0) * 512 + lane * 8);
            ka[kb][1] = *(const short8v*)(Kpl + (kg * 2 + 1) * 512 + lane * 8);
        }
        const int kt = m0 >> 6;
        short8v vf[2][3];
        #pragma unroll
        for (int hh = 0; hh < 2; ++hh)
            #pragma unroll
            for (int db = 0; db < 3; ++db)
                vf[hh][db] = *(const short8v*)(Vpl + (size_t)((kt * 2 + hh) * 3 + db) * 512 + lane * 8);

        f32x4 sf[2][4];
        __builtin_amdgcn_s_setprio(1);
        #pragma unroll
        for (int qi = 0; qi < 2; ++qi)
            #pragma unroll
            for (int kb = 0; kb < 4; ++kb) {
                f32x4 z = {0.f, 0.f, 0.f, 0.f};
                z = __builtin_amdgcn_mfma_f32_16x16x32_bf16(ka[kb][0], qf[qi][0], z, 0, 0, 0);
                z = __builtin_amdgcn_mfma_f32_16x16x32_bf16(ka[kb][1], qf[qi][1], z, 0, 0, 0);
                sf[qi][kb] = z;
            }
        __builtin_amdgcn_s_setprio(0);

        #pragma unroll
        for (int qi = 0; qi < 2; ++qi) {
            float psum = 0.f;
            #pragma unroll
            for (int kb = 0; kb < 4; ++kb) {
                float e0 = __expf(sf[qi][kb][0] - m_i[qi]);
                float e1 = __expf(sf[qi][kb][1] - m_i[qi]);
                float e2 = __expf(sf[qi][kb][2] - m_i[qi]);
                float e3 = __expf(sf[qi][kb][3] - m_i[qi]);
                psum += (e0 + e1) + (e2 + e3);
                u32 r0, r1;
                asm("v_cvt_pk_bf16_f32 %0, %1, %2" : "=v"(r0) : "v"(e0), "v"(e1));
                asm("v_cvt_pk_bf16_f32 %0, %1, %2" : "=v"(r1) : "v"(e2), "v"(e3));
                const int un = (4 * kb + grp) ^ (c7 << 1);
                uint2 pk2; pk2.x = r0; pk2.y = r1;
                *(uint2*)&Pl[wv][qi][col][un << 2] = pk2;
            }
            l_l[qi] += psum;
        }

        __builtin_amdgcn_s_setprio(1);
        #pragma unroll
        for (int qi = 0; qi < 2; ++qi)
            #pragma unroll
            for (int hh = 0; hh < 2; ++hh) {
                const int ur = (8 * hh + 2 * grp) ^ (c7 << 1);
                short8v pf = *(const short8v*)&Pl[wv][qi][col][ur << 2];
                #pragma unroll
                for (int db = 0; db < 3; ++db)
                    acc[qi][db] = __builtin_amdgcn_mfma_f32_16x16x32_bf16(vf[hh][db], pf, acc[qi][db], 0, 0, 0);
            }
        __builtin_amdgcn_s_setprio(0);

        #pragma unroll
        for (int qi = 0; qi < 2; ++qi) {
            float pmax = -1e30f;
            #pragma unroll
            for (int kb = 0; kb < 4; ++kb)
                #pragma unroll
                for (int r = 0; r < 4; ++r) pmax = fmaxf(pmax, sf[qi][kb][r]);
            pmax = fmaxf(pmax, __shfl_xor(pmax, 16, 64));
            pmax = fmaxf(pmax, __shfl_xor(pmax, 32, 64));
            if (!__all(pmax - m_i[qi] <= 8.0f)) {
                float mnew = fmaxf(m_i[qi], pmax);
                float sc = __expf(m_i[qi] - mnew);
                l_l[qi] *= sc;
                #pragma unroll
                for (int db = 0; db < 3; ++db) {
                    acc[qi][db][0] *= sc; acc[qi][db][1] *= sc;
                    acc[qi][db][2] *= sc; acc[qi][db][3] *= sc;
                }
                m_i[qi] = mnew;
            }
        }
    }

    const int ntile = q32 >> 1, qh = q32 & 1;
    const size_t pb = (size_t)(kz * 16 + bh) * 32 + ntile;
    #pragma unroll
    for (int qi = 0; qi < 2; ++qi) {
        float l = l_l[qi];
        l += __shfl_xor(l, 16, 64);
        l += __shfl_xor(l, 32, 64);
        const int q = qh * 32 + qi * 16 + col;
        #pragma unroll
        for (int db = 0; db < 3; ++db)
            #pragma unroll
            for (int r = 0; r < 4; ++r) {
                int d = db * 16 + grp * 4 + r;
                pacc[pb * 3072 + d * 64 + q] = f2bf(acc[qi][db][r]);
            }
        if (grp == 0) {
            pml[pb * 128 + q]      = m_i[qi];
            pml[pb * 128 + 64 + q] = l;
        }
    }
}

// ---------------------------------------------------------------------------
// fused: split-K reduce (blocks 0..511) + graph attention (blocks 512..4607)
// ---------------------------------------------------------------------------
__global__ __launch_bounds__(256) void reduce_graph_kernel(
    const ush* __restrict__ pacc, const float* __restrict__ pml,
    ush* __restrict__ ao,
    const ush* __restrict__ tq, const ush* __restrict__ tv,
    const int* __restrict__ idx, ush* __restrict__ gbuf)
{
    __shared__ float centerf[384];
    __shared__ ush nbr_l[16][384];
    __shared__ float sd[16];
    __shared__ int nbr_i[16];
    const int tid = threadIdx.x;

    if (blockIdx.x < 512) {
        // ============ split-K reduce ============
        const int nt = blockIdx.x & 31, bh = blockIdx.x >> 5;
        const int b = bh >> 3, h = bh & 7;
        const int q = tid & 63, dg = tid >> 6;

        size_t pb[KSPLIT];
        float m[KSPLIT], l[KSPLIT];
        #pragma unroll
        for (int kz = 0; kz < KSPLIT; ++kz) {
            pb[kz] = (size_t)(kz * 16 + bh) * 32 + nt;
            m[kz] = pml[pb[kz] * 128 + q];
            l[kz] = pml[pb[kz] * 128 + 64 + q];
        }
        float ms = -1e30f;
        #pragma unroll
        for (int kz = 0; kz < KSPLIT; ++kz) ms = fmaxf(ms, m[kz]);
        float w[KSPLIT], ls = 0.f;
        #pragma unroll
        for (int kz = 0; kz < KSPLIT; ++kz) { w[kz] = __expf(m[kz] - ms); ls += l[kz] * w[kz]; }
        const float inv = 1.f / ls;

        const size_t hb = ((size_t)(b * C_ + h * 16)) * 3 * N_;
        #pragma unroll
        for (int j = 0; j < 12; ++j) {
            int d = dg * 12 + j;
            float o = 0.f;
            #pragma unroll
            for (int kz = 0; kz < KSPLIT; ++kz)
                o += bf2f(pacc[pb[kz] * 3072 + d * 64 + q]) * w[kz];
            ao[hb + (size_t)d * N_ + nt * 64 + q] = f2bf(o * inv);
        }
    } else {
        // ============ graph attention ============
        const int j = blockIdx.x - 512;
        const int b = j >> 11, n = j & 2047;
        const ush* qrow = tq + (size_t)(b * N_ + n) * 384;
        for (int e = tid; e < 384; e += 256) centerf[e] = bf2f(qrow[e]);
        if (tid < 16) nbr_i[tid] = idx[(size_t)(b * N_ + n) * 16 + tid];
        __syncthreads();

        const int lane = tid & 63, wv = tid >> 6;
        for (int kk = 0; kk < 4; ++kk) {
            int k = wv * 4 + kk;
            const u32* vrow = (const u32*)(tv + ((size_t)b * N_ + nbr_i[k]) * 384);
            float p = 0.f;
            #pragma unroll
            for (int jj = 0; jj < 3; ++jj) {
                int e2 = lane + jj * 64;
                u32 v2 = vrow[e2];
                ((u32*)nbr_l[k])[e2] = v2;
                p += centerf[e2 * 2]     * bf2f((ush)(v2 & 0xffff))
                   + centerf[e2 * 2 + 1] * bf2f((ush)(v2 >> 16));
            }
            #pragma unroll
            for (int off = 32; off; off >>= 1) p += __shfl_down(p, off, 64);
            if (lane == 0) sd[k] = p * 0.05103103630798288f;
        }
        __syncthreads();

        float mx = -1e30f;
        #pragma unroll
        for (int k = 0; k < 16; ++k) mx = fmaxf(mx, sd[k]);
        float a[16]; float ssum = 0.f;
        #pragma unroll
        for (int k = 0; k < 16; ++k) { a[k] = __expf(sd[k] - mx); ssum += a[k]; }
        float inv = 1.f / ssum;

        for (int e = tid; e < 384; e += 256) {
            float accv = 0.f;
            #pragma unroll
            for (int k = 0; k < 16; ++k)
                accv += a[k] * bf2f(nbr_l[k][e]);
            accv *= inv;
            float ce = centerf[e];
            int t = e >> 7, c = e & 127;
            size_t gb = ((size_t)(b * N_ + n) * 3 + t) * 256;
            gbuf[gb + c]       = f2bf(accv - ce);
            gbuf[gb + 128 + c] = f2bf(ce);
        }
    }
}

// ---------------------------------------------------------------------------
// vn_leaky: bf16 x,d in -> bf16 out
// ---------------------------------------------------------------------------
__global__ __launch_bounds__(256) void leaky_kernel(const ush* __restrict__ x,
                                                    const ush* __restrict__ d,
                                                    ush* __restrict__ y)
{
    size_t p = (size_t)blockIdx.x * 256 + threadIdx.x;
    size_t bh = p / N_, n = p % N_;
    size_t base = bh * 3 * N_ + n;
    float x0 = bf2f(x[base]), x1 = bf2f(x[base + N_]), x2 = bf2f(x[base + 2 * N_]);
    float d0 = bf2f(d[base]), d1 = bf2f(d[base + N_]), d2 = bf2f(d[base + 2 * N_]);
    float dot = x0 * d0 + x1 * d1 + x2 * d2;
    float dsq = d0 * d0 + d1 * d1 + d2 * d2;
    float f = dot / (dsq + EPS_);
    bool pos = dot >= 0.f;
    float y0 = pos ? x0 : x0 - f * d0;
    float y1 = pos ? x1 : x1 - f * d1;
    float y2 = pos ? x2 : x2 - f * d2;
    y[base]          = f2bf(NS_ * x0 + (1.f - NS_) * y0);
    y[base + N_]     = f2bf(NS_ * x1 + (1.f - NS_) * y1);
    y[base + 2 * N_] = f2bf(NS_ * x2 + (1.f - NS_) * y2);
}

// ---------------------------------------------------------------------------
extern "C" void kernel_launch(void* const* d_in, const int* in_sizes, int n_in,
                              void* d_out, int out_size, void* d_ws, size_t ws_size,
                              hipStream_t stream)
{
    const float* q_in = (const float*)d_in[0];
    const float* v_in = (const float*)d_in[1];
    const int*   idx_s = (const int*)d_in[4];
    const int*   idx_c = (const int*)d_in[5];
    const float* g1 = (const float*)d_in[6];
    const float* b1 = (const float*)d_in[7];
    const float* g2 = (const float*)d_in[8];
    const float* b2 = (const float*)d_in[9];
    const float* gq = (const float*)d_in[10];
    const float* bq = (const float*)d_in[11];
    const float* gv = (const float*)d_in[12];
    const float* bv = (const float*)d_in[13];
    float* out = (float*)d_out;
    float* ws  = (float*)d_ws;

    const size_t S1 = (size_t)B_ * C_ * 3 * N_; // 1572864 elems
    ush*   gbuf_b= (ush*)(ws);         // 0 (6.3MB; live reduce_graph -> wm2)
    ush*   nx_b  = (ush*)(ws + 2*S1);  // 2 (half)
    ush*   nv_b  = (ush*)(ws + 3*S1);  // 3 (half)
    ush*   vfm   = (ush*)(ws + 4*S1);  // 4: 3MB
    ush*   qktb  = (ush*)(ws + 5*S1) + S1;  // 5.5-6.84: 8.4MB
    ush*   ao_b  = (ush*)(ws + 7*S1);  // 7 (half)
    float* qa    = ws + 12*S1;         // 12
    float* qb    = ws + 13*S1;         // 13
    ush*   t1_b  = (ush*)(ws + 14*S1); // 14 (half)
    ush*   t2_b  = (ush*)(ws + 15*S1); // 15 (half)
    u32*   wsp   = (u32*)(ws + 16*S1); // 16+
    // split-K attention partials (attn->reduce window only; KSPLIT=4: 12.6MB)
    ush*   pacc  = (ush*)(ws + 8*S1);  // 8-9
    float* pml   = (float*)(ws + 2*S1);// 2 (attn after qkv consumed nx_b)
    // phase C aliases (all bf16):
    ush*   hd_b  = (ush*)(ws + 1*S1);  // 1-2 as ush (12.6MB; nv_b/pml dead)
    ush*   h1_b  = (ush*)(ws + 14*S1); // 14-15 (t1/t2 dead)
    ush*   h1_b2 = (ush*)(ws + 8*S1);  // 8-9 (pacc dead)

    // weight planes: 9 split-converted + 4 fused (Wfa/Wfb per phase)
    const int wn[9]   = {16384,16384,16384, 16384,16384,16384, 65536,262144,65536};
    const int wsrc[9] = {14,15,16, 20,21,22, 26,27,28};
    u32* wd[9];
    {
        int off = 0;
        for (int i = 0; i < 9; ++i) { wd[i] = wsp + off; off += wn[i]; }
    }
    u32 *Wq_s = wd[0], *Wk_s = wd[1], *Wv_s = wd[2];
    u32 *Wq_c = wd[3], *Wk_c = wd[4], *Wv_c = wd[5];
    u32 *W1 = wd[6], *Dact = wd[7], *W2 = wd[8];
    u32* Wfa_s = wsp + 491520;
    u32* Wfb_s = Wfa_s + 16384;
    u32* Wfa_c = Wfb_s + 32768;
    u32* Wfb_c = Wfa_c + 16384;

    {
        SetupArgs a{};
        for (int i = 0; i < 9; ++i) {
            a.src[i] = (const float*)d_in[wsrc[i]];
            a.dst[i] = wd[i];
            a.n[i]   = wn[i];
            a.scale[i] = 1.f;
        }
        a.scale[0] = 0.14433756729740643f;  // Wq_s: fold 1/sqrt(48)
        a.scale[3] = 0.14433756729740643f;  // Wq_c
        a.Wm[0] = (const float*)d_in[19]; a.Wo[0] = (const float*)d_in[17]; a.We[0] = (const float*)d_in[18];
        a.Wm[1] = (const float*)d_in[25]; a.Wo[1] = (const float*)d_in[23]; a.We[1] = (const float*)d_in[24];
        a.Wfa[0] = Wfa_s; a.Wfb[0] = Wfb_s;
        a.Wfa[1] = Wfa_c; a.Wfb[1] = Wfb_c;
        a.qkz = (uint4*)qktb;
        setup_kernel<<<dim3(9216 + 384 + 1024), 256, 0, stream>>>(a);
    }

    dim3 gwm(96, 2, B_);
    dim3 gg512(96, 8, B_);

    // ---- Phase A: self attention block ----
    {
        LNArgs la{};
        la.x[0] = q_in; la.g[0] = g1; la.bt[0] = b1; la.ysp[0] = nx_b;
        ln_kernel<<<dim3(64, B_, 1), 256, 0, stream>>>(la);
    }
    {
        QKVArgs A{Wq_s, Wk_s, Wv_s, nx_b, nx_b, nx_b};
        qkv_tr_kernel<<<dim3(1152 + 1536), 256, 0, stream>>>(A, vfm, qktb, nx_b, t1_b, nullptr, nullptr);
    }
    attn_mfma_kernel<<<dim3(1024), 256, 0, stream>>>(vfm, qktb, pacc, pml);
    reduce_graph_kernel<<<dim3(512 + 4096), 256, 0, stream>>>(pacc, pml, ao_b, t1_b, t1_b, idx_s, gbuf_b);
    wm2_kernel<<<gwm, 256, 0, stream>>>(Wfa_s, Wfb_s, ao_b, gbuf_b, q_in, qa);

    // ---- Phase B: cross attention block ----
    {
        LNArgs la{};
        la.x[0] = qa;   la.g[0] = gq; la.bt[0] = bq; la.ysp[0] = nx_b;
        la.x[1] = v_in; la.g[1] = gv; la.bt[1] = bv; la.ysp[1] = nv_b;
        ln_kernel<<<dim3(64, B_, 2), 256, 0, stream>>>(la);
    }
    {
        QKVArgs A{Wq_c, Wk_c, Wv_c, nx_b, nv_b, nv_b};
        qkv_tr_kernel<<<dim3(1152 + 3072), 256, 0, stream>>>(A, vfm, qktb, nx_b, t1_b, nv_b, t2_b);
    }
    attn_mfma_kernel<<<dim3(1024), 256, 0, stream>>>(vfm, qktb, pacc, pml);
    reduce_graph_kernel<<<dim3(512 + 4096), 256, 0, stream>>>(pacc, pml, ao_b, t1_b, t2_b, idx_c, gbuf_b);
    wm2_kernel<<<gwm, 256, 0, stream>>>(Wfa_c, Wfb_c, ao_b, gbuf_b, qa, qb);

    // ---- Phase C: vector MLP (all-bf16 intermediates) ----
    {
        LNArgs la{};
        la.x[0] = qb; la.g[0] = g2; la.bt[0] = b2; la.ysp[0] = nx_b;
        ln_kernel<<<dim3(64, B_, 1), 256, 0, stream>>>(la);
    }
    gemm_kernel2<0,3,true><<<gg512, 256, 0, stream>>>(W1, 128, nx_b, nullptr, nullptr, h1_b, 512, 0, 128);
    gemm_kernel2<0,3,true><<<gg512, 256, 0, stream>>>(Dact, 512, h1_b, nullptr, nullptr, hd_b, 512, 0, 512);
    leaky_kernel<<<dim3((B_ * HID_ * N_) / 256), 256, 0, stream>>>(h1_b, hd_b, h1_b2);
    gemm_kernel2<0,0,true><<<dim3(96, 2, B_), 256, 0, stream>>>(W2, 512, h1_b2, qb, out, nullptr, 128, 0, 512);
}